// Round 10
// baseline (541.740 us; speedup 1.0000x reference)
//
#include <hip/hip_runtime.h>
#include <math.h>

// ---------- model constants ----------
#define NUM_GRAPHS 1024
#define NPG 9
#define NN 9216            // nodes
#define NN2 18432          // batched stage-1 rows (low|high)
#define POSD 64

typedef __attribute__((ext_vector_type(8))) short bf16x8;
typedef __attribute__((ext_vector_type(4))) float f32x4;

__device__ __forceinline__ float gelu_f(float x) {
    return 0.5f * x * (1.0f + erff(x * 0.70710678118654752f));
}
// fast gelu: x*sigmoid(2y) == 0.5x(1+tanh(y)) algebraically (edge aggr only)
__device__ __forceinline__ float gelu_fast(float x) {
    float y2 = 1.5957691216f * x * (1.0f + 0.044715f * x * x);  // 2*sqrt(2/pi)*...
    float t = __expf(fminf(y2, 80.f));
    return x * t * __frcp_rn(t + 1.0f);
}
__device__ __forceinline__ ushort f2b(float v) {
    unsigned u = __float_as_uint(v);
    return (ushort)((u + 0x7fffu + ((u >> 16) & 1u)) >> 16);
}
__device__ __forceinline__ float b2f(ushort u) {
    return __uint_as_float(((unsigned)u) << 16);
}
__device__ __forceinline__ void gload16(const ushort* g, ushort* l) {
    __builtin_amdgcn_global_load_lds((const __attribute__((address_space(1))) void*)g,
                                     (__attribute__((address_space(3))) void*)l, 16, 0, 0);
}

// ---------------------------------------------------------------------------
// bf16 MFMA GEMM, R19: K-loop PHASE STAGGER.
// Evidence (R9): 720 blocks all co-resident -> dispatch wall == single-block
// wall = 56us = ~8.4K cyc/K-step vs ~150 cyc of compute. 94% of the 17.7MB
// per-step staging is L2-served, yet effective L2 delivery is only ~5TB/s:
// all blocks are PHASE-LOCKED on the same k-slab each step (~90 blocks/XCD
// read the same 8KB B-slab lines simultaneously -> L2 line camping).
// Fix: block tix starts its K sweep at step s0 = tix & (nsteps-1), wraps.
// Co-resident blocks now read ~nsteps different k-slabs at any instant.
// (fp32 accumulation order over K rotates; bf16-out tolerance dominates.)
// 256x128 tile, 8 waves, 2-buffer staging, one barrier/step, LDS 48KB.
// C[M,N] = A[M,K]bf16 @ Wt[N,K]^T (+ bias1[n] + prow[(m%9)*ldp+n]) -> bf16
// ---------------------------------------------------------------------------
__global__ __launch_bounds__(512, 4) void mgemm(
    const ushort* __restrict__ A, int lda,
    const ushort* __restrict__ Wt, int ldw,
    const float* __restrict__ bias1,
    const float* __restrict__ prow, int ldp,
    ushort* __restrict__ outB, int ldo, int K)
{
    __shared__ ushort smem[24576];         // 48KB: sA 2x8192 | sB 2x4096
    const int wv = threadIdx.x >> 6, lane = threadIdx.x & 63;
    const int wr = wv >> 1, wc = wv & 1;   // wave's 64x64 quadrant of 256x128

    // ---- XCD-aware bijective remap of (bx,by) [T1, m204 formula] ----
    const int GX = gridDim.x;
    const int nwg = GX * gridDim.y;
    const int flat = blockIdx.y * GX + blockIdx.x;
    const int swq = nwg >> 3, swr = nwg & 7;
    const int xcd = flat & 7, posi = flat >> 3;
    const int tix = (xcd < swr ? xcd * (swq + 1) : swr * (swq + 1) + (xcd - swr) * swq) + posi;
    const int m0 = (tix / GX) * 256, n0 = (tix % GX) * 128;

    f32x4 acc[4][4];
#pragma unroll
    for (int i = 0; i < 4; i++)
#pragma unroll
        for (int j = 0; j < 4; j++) acc[i][j] = (f32x4){0.f, 0.f, 0.f, 0.f};

    const ushort* Ab = A + (size_t)m0 * lda;
    const ushort* Wb = Wt + (size_t)n0 * ldw;

    // 3 gload16 per wave per stage: A chunks {2w,2w+1} (16 total), B chunk {w}
    auto stage = [&](int b, int k0) {
        ushort* sA = smem + b * 8192;
        ushort* sB = smem + 16384 + b * 4096;
#pragma unroll
        for (int i = 0; i < 2; i++) {
            int c = wv * 2 + i;            // 0..15 -> A rows c*16..c*16+15
            int u = c * 64 + lane;
            int row = u >> 2, p = u & 3;
            int q = (p - (row >> 1)) & 3;
            gload16(Ab + (size_t)row * lda + k0 + q * 8, sA + c * 512);
        }
        {
            int c = wv;                    // 0..7 -> B rows c*16..c*16+15
            int u = c * 64 + lane;
            int row = u >> 2, p = u & 3;
            int q = (p - (row >> 1)) & 3;
            gload16(Wb + (size_t)row * ldw + k0 + q * 8, sB + c * 512);
        }
    };

    const int nsteps = K >> 5;             // 8/16/32 (power of 2) at all sites
    const int s0 = tix & (nsteps - 1);     // per-block K-phase stagger
    stage(0, s0 << 5);
    for (int ss = 0; ss < nsteps; ss++) {
        asm volatile("s_waitcnt vmcnt(0)" ::: "memory");   // stage(ss) done
        __builtin_amdgcn_s_barrier();      // all waves' stage(ss) visible;
                                           // step-(ss-1) reads completed pre-barrier
        __builtin_amdgcn_sched_barrier(0);
        if (ss + 1 < nsteps) {
            int nk = ss + 1 + s0; if (nk >= nsteps) nk -= nsteps;
            stage((ss + 1) & 1, nk << 5);  // other buffer, staggered k
        }

        const ushort* sA = smem + (ss & 1) * 8192;
        const ushort* sB = smem + 16384 + (ss & 1) * 4096;
        const int qg = lane >> 4;
        bf16x8 af[4], bfr[4];
#pragma unroll
        for (int bi = 0; bi < 4; bi++) {
            int r = wr * 64 + bi * 16 + (lane & 15);
            af[bi] = *(const bf16x8*)(sA + (r * 4 + ((qg + (r >> 1)) & 3)) * 8);
        }
#pragma unroll
        for (int bj = 0; bj < 4; bj++) {
            int r = wc * 64 + bj * 16 + (lane & 15);
            bfr[bj] = *(const bf16x8*)(sB + (r * 4 + ((qg + (r >> 1)) & 3)) * 8);
        }
        __builtin_amdgcn_s_setprio(1);
#pragma unroll
        for (int bi = 0; bi < 4; bi++)
#pragma unroll
            for (int bj = 0; bj < 4; bj++)
                acc[bi][bj] = __builtin_amdgcn_mfma_f32_16x16x32_bf16(
                    af[bi], bfr[bj], acc[bi][bj], 0, 0, 0);
        __builtin_amdgcn_s_setprio(0);
        __builtin_amdgcn_sched_barrier(0);
    }

    // ---- epilogue: (+prow/bias via LDS) + 2-pass LDS-transpose store ----
    __syncthreads();                       // K-loop LDS dead
    float* sP = (float*)smem;              // 9 x 129 f32 = 4644B (2322 ush)
    const bool haveP = (prow != 0);
    if (haveP) {
        for (int i = threadIdx.x; i < 9 * 128; i += 512) {
            int rr = i >> 7, c = i & 127;
            sP[rr * 129 + c] = prow[(size_t)rr * ldp + n0 + c] + bias1[n0 + c];
        }
        __syncthreads();
    }
    ushort* T = smem + 2560;               // 128 x 136 ush = 17408 (ends 19968)
#pragma unroll
    for (int pass = 0; pass < 2; pass++) {
        if ((wv >> 2) == pass) {           // waves 0-3: rows 0-127; 4-7: 128-255
            int rbase = (wr & 1) * 64;
#pragma unroll
            for (int bi = 0; bi < 4; bi++) {
#pragma unroll
                for (int r = 0; r < 4; r++) {
                    int row_l = rbase + bi * 16 + (lane >> 4) * 4 + r;
                    int r9 = (m0 + pass * 128 + row_l) % 9;
#pragma unroll
                    for (int bj = 0; bj < 4; bj++) {
                        int col = wc * 64 + bj * 16 + (lane & 15);
                        float v = acc[bi][bj][r];
                        if (haveP) v += sP[r9 * 129 + col];
                        T[row_l * 136 + col] = f2b(v);
                    }
                }
            }
        }
        __syncthreads();
        {
            int row_l = threadIdx.x >> 2, qq = threadIdx.x & 3;
            const ushort* src = T + row_l * 136 + qq * 32;
            ushort* dst = outB + (size_t)(m0 + pass * 128 + row_l) * ldo + n0 + qq * 32;
            *(bf16x8*)(dst) = *(const bf16x8*)(src);
            *(bf16x8*)(dst + 8) = *(const bf16x8*)(src + 8);
            *(bf16x8*)(dst + 16) = *(const bf16x8*)(src + 16);
            *(bf16x8*)(dst + 24) = *(const bf16x8*)(src + 24);
        }
        if (pass == 0) __syncthreads();    // before pass 1 overwrites T
    }
}

// ---------------------------------------------------------------------------
// pjgemm: both projections in ONE dispatch. blockIdx.z selects the job
// (z=0: low K=512, z=1: high K=1024); full-K, bias epilogue, bf16 out.
// (128^2 tile, 3-buffer depth-2 — frozen to isolate the stagger variable.)
// ---------------------------------------------------------------------------
struct PJArg {
    const ushort* A[2];
    const ushort* W[2];
    const float*  bias[2];
    ushort*       out[2];
    int lda[2], K[2];
};

__global__ __launch_bounds__(256, 3) void pjgemm(PJArg pa)
{
    __shared__ ushort sA[3][128 * 32];
    __shared__ ushort sB[3][128 * 32];
    const int z = blockIdx.z;
    const ushort* __restrict__ A  = pa.A[z];
    const ushort* __restrict__ Wt = pa.W[z];
    const float*  __restrict__ bias = pa.bias[z];
    ushort* out = pa.out[z];
    const int lda = pa.lda[z], ldw = lda, K = pa.K[z];

    const int wv = threadIdx.x >> 6, lane = threadIdx.x & 63;
    const int rh = wv & 1, ch = wv >> 1;

    const int GX = gridDim.x;
    const int nwg = GX * gridDim.y;
    const int flat = blockIdx.y * GX + blockIdx.x;
    const int swq = nwg >> 3, swr = nwg & 7;
    const int xcd = flat & 7, posi = flat >> 3;
    const int tix = (xcd < swr ? xcd * (swq + 1) : swr * (swq + 1) + (xcd - swr) * swq) + posi;
    const int m0 = (tix / GX) * 128, n0 = (tix % GX) * 128;

    f32x4 acc[4][4];
#pragma unroll
    for (int i = 0; i < 4; i++)
#pragma unroll
        for (int j = 0; j < 4; j++) acc[i][j] = (f32x4){0.f, 0.f, 0.f, 0.f};

    const ushort* Ab = A + (size_t)m0 * lda;
    const ushort* Wb = Wt + (size_t)n0 * ldw;

    auto stage = [&](int b, int k0) {
#pragma unroll
        for (int i = 0; i < 2; i++) {
            int c = wv * 2 + i;
            int u = c * 64 + lane;
            int row = u >> 2, p = u & 3;
            int q = (p - (row >> 1)) & 3;
            gload16(Ab + (size_t)row * lda + k0 + q * 8, sA[b] + c * 512);
            gload16(Wb + (size_t)row * ldw + k0 + q * 8, sB[b] + c * 512);
        }
    };

    const int nsteps = K >> 5;       // 16 or 32
    stage(0, 0);
    stage(1, 32);
    int cur = 0;
    for (int s = 0; s < nsteps; s++) {
        if (s + 1 < nsteps) {
            asm volatile("s_waitcnt vmcnt(4)" ::: "memory");
        } else {
            asm volatile("s_waitcnt vmcnt(0)" ::: "memory");
        }
        __builtin_amdgcn_s_barrier();
        __builtin_amdgcn_sched_barrier(0);
        if (s + 2 < nsteps) {
            int nb = cur + 2; if (nb >= 3) nb -= 3;
            stage(nb, (s + 2) << 5);
        }

        const int qg = lane >> 4;
        bf16x8 af[4], bfr[4];
#pragma unroll
        for (int bi = 0; bi < 4; bi++) {
            int r = rh * 64 + bi * 16 + (lane & 15);
            af[bi] = *(const bf16x8*)(sA[cur] + (r * 4 + ((qg + (r >> 1)) & 3)) * 8);
        }
#pragma unroll
        for (int bj = 0; bj < 4; bj++) {
            int r = ch * 64 + bj * 16 + (lane & 15);
            bfr[bj] = *(const bf16x8*)(sB[cur] + (r * 4 + ((qg + (r >> 1)) & 3)) * 8);
        }
        __builtin_amdgcn_s_setprio(1);
#pragma unroll
        for (int bi = 0; bi < 4; bi++)
#pragma unroll
            for (int bj = 0; bj < 4; bj++)
                acc[bi][bj] = __builtin_amdgcn_mfma_f32_16x16x32_bf16(
                    af[bi], bfr[bj], acc[bi][bj], 0, 0, 0);
        __builtin_amdgcn_s_setprio(0);
        __builtin_amdgcn_sched_barrier(0);
        cur++; if (cur >= 3) cur -= 3;
    }

    // epilogue: + bias[n], write bf16
    float* sBias = (float*)sA;
    __syncthreads();
    if (threadIdx.x < 128) sBias[threadIdx.x] = bias[n0 + threadIdx.x];
    __syncthreads();

#pragma unroll
    for (int bi = 0; bi < 4; bi++) {
#pragma unroll
        for (int r = 0; r < 4; r++) {
            int m = m0 + rh * 64 + bi * 16 + (lane >> 4) * 4 + r;
#pragma unroll
            for (int bj = 0; bj < 4; bj++) {
                int nc = ch * 64 + bj * 16 + (lane & 15);
                float v = acc[bi][bj][r] + sBias[nc];
                out[(size_t)m * 512 + n0 + nc] = f2b(v);
            }
        }
    }
}

// ---------------------------------------------------------------------------
// weight transpose+convert: out[n*ldo + k] = bf16(src[(off0+k)*N + n])
// ---------------------------------------------------------------------------
#define NJOBS 16
struct TJobsArg {
    const float* src[NJOBS];
    long dst[NJOBS];
    int K[NJOBS], N[NJOBS], off0[NJOBS], ldo[NJOBS];
};

__global__ __launch_bounds__(256) void tw_kernel(TJobsArg ja, ushort* wbuf)
{
    int j = blockIdx.y;
    int K = ja.K[j], N = ja.N[j];
    int tk = K >> 5, tn = N >> 5;
    int t = blockIdx.x;
    if (t >= tk * tn) return;
    int kt = t % tk, nt = t / tk;
    const float* src = ja.src[j];
    ushort* out = wbuf + ja.dst[j];
    int ldo = ja.ldo[j];
    __shared__ float L[32][33];
    int r = threadIdx.x >> 5, c = threadIdx.x & 31;
#pragma unroll
    for (int rr = 0; rr < 4; rr++) {
        int k = kt * 32 + rr * 8 + r;
        L[rr * 8 + r][c] = src[(size_t)(ja.off0[j] + k) * N + nt * 32 + c];
    }
    __syncthreads();
#pragma unroll
    for (int rr = 0; rr < 4; rr++) {
        int n = nt * 32 + rr * 8 + r;
        out[(size_t)n * ldo + kt * 32 + c] = f2b(L[c][rr * 8 + r]);
    }
}

// ---------------------------------------------------------------------------
// Graph-per-block edge kernel, templated on O (compile-time strides).
// Two-phase staging: AdAs -> logits -> restage PdPs under softmax.
// PB row n: [Pd(O)|Ps(O)|Ad(O)|As(O)|skip(O)].
// ---------------------------------------------------------------------------
template<int O>
__global__ __launch_bounds__(256) void edge_kernel_t(
    const ushort* __restrict__ PB, const float* __restrict__ att2_w,
    ushort* __restrict__ Gout, int ldG, float* __restrict__ S)
{
    constexpr int O2 = O * 2, O5 = O * 5;
    constexpr int tpr = O >> 8;
    constexpr int tcount = 9 * tpr;
    constexpr int nch = O >> 3;
    constexpr int cshift = (O == 256) ? 5 : 6;
    constexpr int E = O >> 6;
    __shared__ ushort sPB[9 * O2];
    __shared__ float sAw[O];
    __shared__ float logits[72];
    __shared__ float aw[72];
    const int g = blockIdx.x;
    const int tid = threadIdx.x, lane = tid & 63, wave = tid >> 6;
    const ushort* gbase = PB + (size_t)g * 9 * O5;

    // phase A: stage Ad|As (cols [2O,4O) of each PB row)
    for (int i = wave; i < tcount; i += 4) {
        int row = i / tpr, co = i - row * tpr;
        gload16(gbase + (size_t)row * O5 + O2 + co * 512 + lane * 8, sPB + i * 512);
    }
    for (int c = tid; c < O; c += 256) sAw[c] = att2_w[c];
    __syncthreads();

    for (int e = wave; e < 72; e += 4) {
        int d = e >> 3, k = e & 7;
        int s = k + (k >= d);
        const ushort* ad = sPB + d * O2 + lane * E;
        const ushort* as = sPB + s * O2 + O + lane * E;
        const float* wp = sAw + lane * E;
        float p = 0.f;
        if constexpr (E == 4) {
            ushort4 a4 = *(const ushort4*)ad;
            ushort4 s4 = *(const ushort4*)as;
            float4 w4 = *(const float4*)wp;
            const ushort* ap = (const ushort*)&a4;
            const ushort* sp = (const ushort*)&s4;
            const float* wf = (const float*)&w4;
#pragma unroll
            for (int j = 0; j < 4; j++) {
                float v = b2f(ap[j]) + b2f(sp[j]);
                v = fmaxf(v, 0.01f * v);
                p += v * wf[j];
            }
        } else {
            bf16x8 a8 = *(const bf16x8*)ad;
            bf16x8 s8 = *(const bf16x8*)as;
            float4 w0 = *(const float4*)wp;
            float4 w1 = *(const float4*)(wp + 4);
            const ushort* ap = (const ushort*)&a8;
            const ushort* sp = (const ushort*)&s8;
            const float wf[8] = {w0.x, w0.y, w0.z, w0.w, w1.x, w1.y, w1.z, w1.w};
#pragma unroll
            for (int j = 0; j < 8; j++) {
                float v = b2f(ap[j]) + b2f(sp[j]);
                v = fmaxf(v, 0.01f * v);
                p += v * wf[j];
            }
        }
#pragma unroll
        for (int off = 32; off; off >>= 1) p += __shfl_down(p, off, 64);
        if (lane == 0) logits[e] = p;     // att2_b cancels in softmax
    }
    __syncthreads();                      // AdAs reads complete

    // phase B: restage Pd|Ps (cols [0,2O)) over the same buffer;
    // latency hides under softmax below.
    for (int i = wave; i < tcount; i += 4) {
        int row = i / tpr, co = i - row * tpr;
        gload16(gbase + (size_t)row * O5 + co * 512 + lane * 8, sPB + i * 512);
    }

    if (tid < 9) {
        float m = -INFINITY;
#pragma unroll
        for (int k = 0; k < 8; k++) m = fmaxf(m, logits[tid * 8 + k]);
        float s = 0.f, ee[8];
#pragma unroll
        for (int k = 0; k < 8; k++) { ee[k] = expf(logits[tid * 8 + k] - m); s += ee[k]; }
        float inv = 1.0f / (s + 1e-16f);
#pragma unroll
        for (int k = 0; k < 8; k++) aw[tid * 8 + k] = ee[k] * inv;
        S[g * 9 + tid] = s * inv;
    }
    __syncthreads();                      // drains vmcnt -> PdPs staged; aw ready

    for (int idx = tid; idx < 9 * nch; idx += 256) {
        int n = idx >> cshift, cc = idx & (nch - 1);
        bf16x8 pdv = *(const bf16x8*)(sPB + n * O2 + cc * 8);
        const ushort* pp = (const ushort*)&pdv;
        float pdf[8];
#pragma unroll
        for (int j = 0; j < 8; j++) pdf[j] = b2f(pp[j]);
        float acc8[8];
#pragma unroll
        for (int j = 0; j < 8; j++) acc8[j] = 0.f;
#pragma unroll
        for (int k = 0; k < 8; k++) {
            int s = k + (k >= n);
            float w = aw[n * 8 + k];
            bf16x8 psv = *(const bf16x8*)(sPB + s * O2 + O + cc * 8);
            const ushort* qp = (const ushort*)&psv;
#pragma unroll
            for (int j = 0; j < 8; j++)
                acc8[j] += w * gelu_fast(pdf[j] + b2f(qp[j]));
        }
        ushort o8[8];
#pragma unroll
        for (int j = 0; j < 8; j++) o8[j] = f2b(acc8[j]);
        *(bf16x8*)(Gout + (size_t)(g * 9 + n) * ldG + cc * 8) = *(const bf16x8*)o8;
    }
}

// ---------------------------------------------------------------------------
// Fused upd-epilogue + LayerNorm, wave-per-row, bf16 partials P0:
//   t = bf16(P0) + ub[c] + vb[c]*S[n] + posU[(n%9)*O+c];
//   h = gelu(t) + skip(bf16);  LN(h) -> outB bf16 (row remap) or outF fp32
// ---------------------------------------------------------------------------
__global__ __launch_bounds__(256) void ln_kernel(
    const ushort* __restrict__ P0,
    const float* __restrict__ ub, const float* __restrict__ vb,
    const float* __restrict__ S, const float* __restrict__ posU,
    const ushort* __restrict__ PBs, int ld5,
    const float* __restrict__ gw, const float* __restrict__ bw,
    ushort* outB, int ldoB, int rowsplit, float* outF, int O)
{
    const int wid = threadIdx.x >> 6, lane = threadIdx.x & 63;
    const int n = blockIdx.x * 4 + wid;
    const float sv = S[n];
    const ushort* p0 = P0 + (size_t)n * O;
    const ushort* sr = PBs + (size_t)n * ld5;
    const float* pu = posU + (size_t)(n % 9) * O;
    const int q = O >> 6;              // 4 or 8 elems per lane
    const int c0 = lane * q;

    float vals[8];
    float sum = 0.f;
    if (O == 256) {
        ushort4 pv = *(const ushort4*)(p0 + c0);
        ushort4 sk = *(const ushort4*)(sr + c0);
        float4 uu = *(const float4*)(ub + c0);
        float4 vv = *(const float4*)(vb + c0);
        float4 gg = *(const float4*)(pu + c0);
        const ushort tp[4] = {pv.x, pv.y, pv.z, pv.w};
        const ushort ts[4] = {sk.x, sk.y, sk.z, sk.w};
        const float tu[4] = {uu.x, uu.y, uu.z, uu.w};
        const float tv[4] = {vv.x, vv.y, vv.z, vv.w};
        const float tg[4] = {gg.x, gg.y, gg.z, gg.w};
#pragma unroll
        for (int j = 0; j < 4; j++) {
            float t = b2f(tp[j]) + tu[j] + tv[j] * sv + tg[j];
            vals[j] = gelu_f(t) + b2f(ts[j]);
            sum += vals[j];
        }
    } else {                           // O == 512
        bf16x8 pv = *(const bf16x8*)(p0 + c0);
        bf16x8 sk = *(const bf16x8*)(sr + c0);
        const ushort* tp = (const ushort*)&pv;
        const ushort* ts = (const ushort*)&sk;
        float4 u0 = *(const float4*)(ub + c0), u1 = *(const float4*)(ub + c0 + 4);
        float4 v0 = *(const float4*)(vb + c0), v1 = *(const float4*)(vb + c0 + 4);
        float4 g0 = *(const float4*)(pu + c0), g1 = *(const float4*)(pu + c0 + 4);
        const float tu[8] = {u0.x,u0.y,u0.z,u0.w, u1.x,u1.y,u1.z,u1.w};
        const float tv[8] = {v0.x,v0.y,v0.z,v0.w, v1.x,v1.y,v1.z,v1.w};
        const float tg[8] = {g0.x,g0.y,g0.z,g0.w, g1.x,g1.y,g1.z,g1.w};
#pragma unroll
        for (int j = 0; j < 8; j++) {
            float t = b2f(tp[j]) + tu[j] + tv[j] * sv + tg[j];
            vals[j] = gelu_f(t) + b2f(ts[j]);
            sum += vals[j];
        }
    }

#pragma unroll
    for (int off = 32; off; off >>= 1) sum += __shfl_xor(sum, off, 64);
    const float mu = sum / (float)O;
    float var = 0.f;
#pragma unroll
    for (int j = 0; j < 8; j++) {
        if (j < q) { float d = vals[j] - mu; var += d * d; }
    }
#pragma unroll
    for (int off = 32; off; off >>= 1) var += __shfl_xor(var, off, 64);
    const float rstd = rsqrtf(var / (float)O + 1e-5f);

    int orow = n, coloff = 0;
    if (n >= rowsplit) { orow = n - rowsplit; coloff = 256; }

    if (outB) {
        ushort o[8];
#pragma unroll
        for (int j = 0; j < 8; j++) {
            if (j < q) o[j] = f2b((vals[j] - mu) * rstd * gw[c0 + j] + bw[c0 + j]);
        }
        ushort* dst = outB + (size_t)orow * ldoB + coloff + c0;
        if (q == 4) *(ushort4*)dst = *(const ushort4*)o;
        else        *(bf16x8*)dst = *(const bf16x8*)o;
    }
    if (outF) {
        float* dst = outF + (size_t)n * O + c0;
#pragma unroll
        for (int j = 0; j < 8; j++) {
            if (j < q) dst[j] = (vals[j] - mu) * rstd * gw[c0 + j] + bw[c0 + j];
        }
    }
}

// ---------------------------------------------------------------------------
// prep: concat biases, pos tables (posPB/posU), vb, pw2 bf16 copies,
//       and feat_low/feat_high fp32->bf16 conversion (merged f2b)
// ---------------------------------------------------------------------------
__global__ void prep_kernel(
    const float* __restrict__ pw1_b1, const float* __restrict__ att1_b1, const float* __restrict__ skip_b1,
    const float* __restrict__ pw1_b2, const float* __restrict__ att1_b2, const float* __restrict__ skip_b2,
    const float* __restrict__ pos_table,
    const float* __restrict__ s1_pw1, const float* __restrict__ s1_att, const float* __restrict__ s1_skp,
    const float* __restrict__ s2_pw1, const float* __restrict__ s2_att, const float* __restrict__ s2_skp,
    const float* __restrict__ pw2_b1, const float* __restrict__ upd_w1,
    const float* __restrict__ pw2_b2, const float* __restrict__ upd_w2,
    const float* __restrict__ pw2_w1, const float* __restrict__ pw2_w2,
    const float* __restrict__ feat_low, const float* __restrict__ feat_high,
    float* biasC1, float* biasC2,
    float* posPB1, float* posPB2, float* posU1, float* posU2,
    float* vb1, float* vb2, ushort* pw2f1, ushort* pw2f2, ushort* featB)
{
    int i = blockIdx.x * 256 + threadIdx.x;
    if (i < 1280) {
        float v;
        if (i < 256) v = pw1_b1[i];
        else if (i < 512) v = 0.f;
        else if (i < 768) v = att1_b1[i - 512];
        else if (i < 1024) v = 0.f;
        else v = skip_b1[i - 1024];
        biasC1[i] = v;
        return;
    }
    i -= 1280;
    if (i < 2560) {
        float v;
        if (i < 512) v = pw1_b2[i];
        else if (i < 1024) v = 0.f;
        else if (i < 1536) v = att1_b2[i - 1024];
        else if (i < 2048) v = 0.f;
        else v = skip_b2[i - 2048];
        biasC2[i] = v;
        return;
    }
    i -= 2560;
    if (i < 9 * 1280) {   // posPB1[r][n]
        int r = i / 1280, n = i - r * 1280;
        int sec = n >> 8, c = n & 255;
        const float* src; int row0;
        if (sec == 0) { src = s1_pw1; row0 = 256; }
        else if (sec == 1) { src = s1_pw1; row0 = 576; }
        else if (sec == 2) { src = s1_att; row0 = 512; }
        else if (sec == 3) { src = s1_att; row0 = 576; }
        else { src = s1_skp; row0 = 256; }
        float a = 0.f;
        for (int k = 0; k < 64; k++) a += pos_table[r * 64 + k] * src[(size_t)(row0 + k) * 256 + c];
        posPB1[i] = a;
        return;
    }
    i -= 9 * 1280;
    if (i < 9 * 2560) {   // posPB2[r][n]
        int r = i / 2560, n = i - r * 2560;
        int sec = n >> 9, c = n & 511;
        const float* src; int row0;
        if (sec == 0) { src = s2_pw1; row0 = 512; }
        else if (sec == 1) { src = s2_pw1; row0 = 1088; }
        else if (sec == 2) { src = s2_att; row0 = 1024; }
        else if (sec == 3) { src = s2_att; row0 = 1088; }
        else { src = s2_skp; row0 = 512; }
        float a = 0.f;
        for (int k = 0; k < 64; k++) a += pos_table[r * 64 + k] * src[(size_t)(row0 + k) * 512 + c];
        posPB2[i] = a;
        return;
    }
    i -= 9 * 2560;
    if (i < 9 * 256) {    // posU1
        int r = i >> 8, c = i & 255;
        float a = 0.f;
        for (int k = 0; k < 64; k++) a += pos_table[r * 64 + k] * upd_w1[(size_t)(256 + k) * 256 + c];
        posU1[i] = a;
        return;
    }
    i -= 9 * 256;
    if (i < 9 * 512) {    // posU2
        int r = i >> 9, c = i & 511;
        float a = 0.f;
        for (int k = 0; k < 64; k++) a += pos_table[r * 64 + k] * upd_w2[(size_t)(512 + k) * 512 + c];
        posU2[i] = a;
        return;
    }
    i -= 9 * 512;
    if (i < 256) {        // vb1[n] = sum_j pw2_b1[j] * upd_w1[(320+j)][n]
        float a = 0.f;
        for (int j = 0; j < 256; j++) a += pw2_b1[j] * upd_w1[(size_t)(320 + j) * 256 + i];
        vb1[i] = a;
        return;
    }
    i -= 256;
    if (i < 512) {        // vb2
        float a = 0.f;
        for (int j = 0; j < 512; j++) a += pw2_b2[j] * upd_w2[(size_t)(576 + j) * 512 + i];
        vb2[i] = a;
        return;
    }
    i -= 512;
    if (i < 256 * 256) { pw2f1[i] = f2b(pw2_w1[i]); return; }
    i -= 256 * 256;
    if (i < 512 * 512) { pw2f2[i] = f2b(pw2_w2[i]); return; }
    i -= 512 * 512;
    if (i < NN * 512 / 4) {   // feat_low -> featB bf16
        float4 v = ((const float4*)feat_low)[i];
        ushort4 o;
        o.x = f2b(v.x); o.y = f2b(v.y); o.z = f2b(v.z); o.w = f2b(v.w);
        ((ushort4*)featB)[i] = o;
        return;
    }
    i -= NN * 512 / 4;
    if (i < NN * 1024 / 4) {  // feat_high -> featB + NN*512
        float4 v = ((const float4*)feat_high)[i];
        ushort4 o;
        o.x = f2b(v.x); o.y = f2b(v.y); o.z = f2b(v.z); o.w = f2b(v.w);
        ((ushort4*)(featB + (size_t)NN * 512))[i] = o;
    }
}

// ---------------------------------------------------------------------------
// head: pool(9 rows) + cls1 (gelu) + cls2, 4 graphs per block
// ---------------------------------------------------------------------------
__global__ __launch_bounds__(256) void head_kernel(
    const float* __restrict__ h2,
    const float* __restrict__ cls1_w, const float* __restrict__ cls1_b,
    const float* __restrict__ cls2_w, const float* __restrict__ cls2_b,
    float* __restrict__ out)
{
    __shared__ float pooled[4][512];
    __shared__ float hid[4][256];
    const int b = blockIdx.x, tid = threadIdx.x;

    for (int idx = tid; idx < 4 * 512; idx += 256) {
        int gi = idx >> 9, c = idx & 511;
        const float* base = h2 + (size_t)((b * 4 + gi) * 9) * 512 + c;
        float s = 0.f;
#pragma unroll
        for (int k = 0; k < NPG; k++) s += base[(size_t)k * 512];
        pooled[gi][c] = s;
    }
    __syncthreads();

    {
        float acc[4] = {0.f, 0.f, 0.f, 0.f};
        for (int c = 0; c < 512; c++) {
            float w = cls1_w[(size_t)c * 256 + tid];
#pragma unroll
            for (int gi = 0; gi < 4; gi++) acc[gi] += pooled[gi][c] * w;
        }
        float bb = cls1_b[tid];
#pragma unroll
        for (int gi = 0; gi < 4; gi++) hid[gi][tid] = gelu_f(acc[gi] + bb);
    }
    __syncthreads();

    {
        int gi = tid >> 6, lane = tid & 63;
        float p = 0.f;
#pragma unroll
        for (int i = 0; i < 4; i++) p += hid[gi][lane + 64 * i] * cls2_w[lane + 64 * i];
#pragma unroll
        for (int off = 32; off; off >>= 1) p += __shfl_down(p, off, 64);
        if (lane == 0) out[b * 4 + gi] = p + cls2_b[0];
    }
}

// ---------------------------------------------------------------------------
// Host side
// ---------------------------------------------------------------------------
static inline void mg(hipStream_t st, int M, int N, int K,
                      const ushort* A, int lda, const ushort* Wt, int ldw,
                      const float* bias1, const float* prow, int ldp,
                      ushort* outB, int ldo)
{
    dim3 grid(N / 128, M / 256);           // BM=256
    mgemm<<<grid, dim3(512), 0, st>>>(A, lda, Wt, ldw, bias1, prow, ldp,
                                      outB, ldo, K);
}

extern "C" void kernel_launch(void* const* d_in, const int* in_sizes, int n_in,
                              void* d_out, int out_size, void* d_ws, size_t ws_size,
                              hipStream_t stream)
{
    (void)in_sizes; (void)n_in; (void)out_size; (void)ws_size;
    const float* feat_low   = (const float*)d_in[0];
    const float* feat_high  = (const float*)d_in[1];
    const float* pos_table  = (const float*)d_in[4];
    const float* proj_low_w  = (const float*)d_in[5];
    const float* proj_low_b  = (const float*)d_in[6];
    const float* proj_high_w = (const float*)d_in[7];
    const float* proj_high_b = (const float*)d_in[8];
    const float* cls1_w = (const float*)d_in[37];
    const float* cls1_b = (const float*)d_in[38];
    const float* cls2_w = (const float*)d_in[39];
    const float* cls2_b = (const float*)d_in[40];
    float* out = (float*)d_out;

    const float* s1_pw1 = (const float*)d_in[9];
    const float* s1_att = (const float*)d_in[13];
    const float* s1_upd = (const float*)d_in[17];
    const float* s1_skp = (const float*)d_in[21];
    const float* s2_pw1 = (const float*)d_in[23];
    const float* s2_att = (const float*)d_in[27];
    const float* s2_upd = (const float*)d_in[31];
    const float* s2_skp = (const float*)d_in[35];

    const float* att2_w1 = (const float*)d_in[15];
    const float* upd_b1  = (const float*)d_in[18];
    const float* ln_g1   = (const float*)d_in[19];
    const float* ln_b1   = (const float*)d_in[20];
    const float* att2_w2 = (const float*)d_in[29];
    const float* upd_b2  = (const float*)d_in[32];
    const float* ln_g2   = (const float*)d_in[33];
    const float* ln_b2   = (const float*)d_in[34];

    // ---- workspace layout (256B aligned) ----
    char* base = (char*)d_ws;
    size_t cur = 0;
    auto alloc = [&](size_t bytes) { void* p = base + cur; cur += (bytes + 255) & ~(size_t)255; return p; };
    void*   PBreg = alloc((size_t)NN * 2560 * 2);   // PB (s1: 18432x1280, s2: 9216x2560); featB alias
    ushort* PB    = (ushort*)PBreg;
    ushort* featB = (ushort*)PBreg;
    void*   IX1reg = alloc((size_t)NN2 * 512 * 2);  // ixa1 bf16; h2 fp32 alias (disjoint in time)
    ushort* ixa1  = (ushort*)IX1reg;
    float*  h2    = (float*)IX1reg;
    ushort* ixa2  = (ushort*)alloc((size_t)NN * 1024 * 2);
    ushort* PT    = (ushort*)alloc((size_t)NN2 * 512 * 2);  // upd bf16 partials
    float*  S     = (float*)alloc((size_t)NN2 * 4);
    float*  biasC1 = (float*)alloc(1280 * 4);
    float*  biasC2 = (float*)alloc(2560 * 4);
    float*  posPB1 = (float*)alloc(9 * 1280 * 4);
    float*  posPB2 = (float*)alloc(9 * 2560 * 4);
    float*  posU1  = (float*)alloc(9 * 256 * 4);
    float*  posU2  = (float*)alloc(9 * 512 * 4);
    float*  vb1   = (float*)alloc(256 * 4);
    float*  vb2   = (float*)alloc(512 * 4);
    ushort* wbuf  = (ushort*)alloc((size_t)3400000 * 2);

    // ---- weight transpose jobs (x-parts only; pos handled via prow tables) ----
    TJobsArg ja;
    long woff[16];
    {
        struct J { const float* s; int K, N, off0, ldo; long sz; };
        J js[NJOBS] = {
            {proj_low_w,  512, 256, 0, 512, 512L * 256},     // 0 projL
            {proj_high_w, 1024, 256, 0, 1024, 1024L * 256},  // 1 projH
            {s1_pw1, 256, 256, 0, 256, 256L * 256},          // 2 big5-1: pw1d
            {s1_pw1, 256, 256, 320, 256, 256L * 256},        // 3 pw1s
            {s1_att, 256, 256, 0, 256, 256L * 256},          // 4 attd
            {s1_att, 256, 256, 256, 256, 256L * 256},        // 5 atts
            {s1_skp, 256, 256, 0, 256, 256L * 256},          // 6 skip
            {s1_upd, 256, 256, 0, 512, 512L * 256},          // 7 updW1 (x cols)
            {s1_upd, 256, 256, 320, 256, 256L * 256},        // 8 updbT1 (aggr rows)
            {s2_pw1, 512, 512, 0, 512, 512L * 512},          // 9 big5-2: pw1d
            {s2_pw1, 512, 512, 576, 512, 512L * 512},        // 10 pw1s
            {s2_att, 512, 512, 0, 512, 512L * 512},          // 11 attd
            {s2_att, 512, 512, 512, 512, 512L * 512},        // 12 atts
            {s2_skp, 512, 512, 0, 512, 512L * 512},          // 13 skip
            {s2_upd, 512, 512, 0, 1024, 1024L * 512},        // 14 updW2 (x cols)
            {s2_upd, 512, 512, 576, 512, 512L * 512},        // 15 updbT2
        };
        long off = 0;
        for (int i = 0; i < NJOBS; i++) {
            ja.src[i] = js[i].s; ja.K[i] = js[i].K; ja.N[i] = js[i].N;
            ja.off0[i] = js[i].off0; ja.ldo[i] = js[i].ldo;
            ja.dst[i] = off; woff[i] = off;
            off += js[i].sz;
        }
    }
    long pw2off1 = woff[15] + 512L * 512;
    long pw2off2 = pw2off1 + 256L * 256;
    tw_kernel<<<dim3(256, NJOBS), dim3(256), 0, stream>>>(ja, wbuf);

    ushort* wBig5_1 = wbuf + woff[2];
    ushort* updW1   = wbuf + woff[7];
    ushort* updbT1  = wbuf + woff[8];
    ushort* wBig5_2 = wbuf + woff[9];
    ushort* updW2   = wbuf + woff[14];
    ushort* updbT2  = wbuf + woff[15];
    ushort* pw2f1   = wbuf + pw2off1;
    ushort* pw2f2   = wbuf + pw2off2;

    // ---- prep (biases, pos tables, vb, pw2 bf16, feat->bf16) ----
    {
        long tot = 1280 + 2560 + 9 * 1280 + 9 * 2560 + 9 * 256 + 9 * 512
                 + 256 + 512 + 256 * 256 + 512 * 512
                 + (long)NN * 512 / 4 + (long)NN * 1024 / 4;
        prep_kernel<<<dim3((unsigned)((tot + 255) / 256)), dim3(256), 0, stream>>>(
            (const float*)d_in[10], (const float*)d_in[14], (const float*)d_in[22],
            (const float*)d_in[24], (const float*)d_in[28], (const float*)d_in[36],
            pos_table,
            s1_pw1, s1_att, s1_skp, s2_pw1, s2_att, s2_skp,
            (const float*)d_in[12], s1_upd, (const float*)d_in[26], s2_upd,
            (const float*)d_in[11], (const float*)d_in[25],
            feat_low, feat_high,
            biasC1, biasC2, posPB1, posPB2, posU1, posU2, vb1, vb2, pw2f1, pw2f2, featB);
    }

    // ---- Wcomb = pw2 @ updb, transposed into updW G-columns ----
    mg(stream, 256, 256, 256, updbT1, 256, pw2f1, 256, 0, 0, 0, updW1 + 256, 512);
    mg(stream, 512, 512, 512, updbT2, 512, pw2f2, 512, 0, 0, 0, updW2 + 512, 1024);

    // ---- projections: ONE fused dispatch, full-K, direct bf16 + bias ----
    {
        PJArg pa;
        pa.A[0] = featB;                      pa.lda[0] = 512;  pa.K[0] = 512;
        pa.A[1] = featB + (size_t)NN * 512;   pa.lda[1] = 1024; pa.K[1] = 1024;
        pa.W[0] = wbuf + woff[0];
        pa.W[1] = wbuf + woff[1];
        pa.bias[0] = proj_low_b;
        pa.bias[1] = proj_high_b;
        pa.out[0] = ixa1;
        pa.out[1] = ixa1 + (size_t)NN * 512;
        pjgemm<<<dim3(2, NN / 128, 2), dim3(256), 0, stream>>>(pa);
    }

    // ---- stage 1 (batched, M = 18432) ----
    mg(stream, NN2, 1280, 256, ixa1, 512, wBig5_1, 256, biasC1, posPB1, 1280, PB, 1280);
    edge_kernel_t<256><<<dim3(2 * NUM_GRAPHS), dim3(256), 0, stream>>>(
        PB, att2_w1, ixa1 + 256, 512, S);
    mg(stream, NN2, 256, 512, ixa1, 512, updW1, 512, 0, 0, 0, PT, 256);
    ln_kernel<<<dim3(NN2 / 4), dim3(256), 0, stream>>>(
        PT, upd_b1, vb1, S, posU1,
        PB + 4 * 256, 1280, ln_g1, ln_b1, ixa2, 1024, NN, 0, 256);

    // ---- stage 2 ----
    mg(stream, NN, 2560, 512, ixa2, 1024, wBig5_2, 512, biasC2, posPB2, 2560, PB, 2560);
    edge_kernel_t<512><<<dim3(NUM_GRAPHS), dim3(256), 0, stream>>>(
        PB, att2_w2, ixa2 + 512, 1024, S);
    mg(stream, NN, 512, 1024, ixa2, 1024, updW2, 1024, 0, 0, 0, PT, 512);
    ln_kernel<<<dim3(NN / 4), dim3(256), 0, stream>>>(
        PT, upd_b2, vb2, S, posU2,
        PB + 4 * 512, 2560, ln_g2, ln_b2, 0, 0, 1 << 30, h2, 512);

    // ---- head ----
    head_kernel<<<dim3(NUM_GRAPHS / 4), dim3(256), 0, stream>>>(h2, cls1_w, cls1_b, cls2_w, cls2_b, out);
}

// Round 11
// 535.347 us; speedup vs baseline: 1.0119x; 1.0119x over previous
//
#include <hip/hip_runtime.h>
#include <math.h>

// ---------- model constants ----------
#define NUM_GRAPHS 1024
#define NPG 9
#define NN 9216            // nodes
#define NN2 18432          // batched stage-1 rows (low|high)
#define POSD 64

typedef __attribute__((ext_vector_type(8))) short bf16x8;
typedef __attribute__((ext_vector_type(4))) float f32x4;

__device__ __forceinline__ float gelu_f(float x) {
    return 0.5f * x * (1.0f + erff(x * 0.70710678118654752f));
}
// fast gelu: x*sigmoid(2y) == 0.5x(1+tanh(y)) algebraically (edge aggr only)
__device__ __forceinline__ float gelu_fast(float x) {
    float y2 = 1.5957691216f * x * (1.0f + 0.044715f * x * x);  // 2*sqrt(2/pi)*...
    float t = __expf(fminf(y2, 80.f));
    return x * t * __frcp_rn(t + 1.0f);
}
__device__ __forceinline__ ushort f2b(float v) {
    unsigned u = __float_as_uint(v);
    return (ushort)((u + 0x7fffu + ((u >> 16) & 1u)) >> 16);
}
__device__ __forceinline__ float b2f(ushort u) {
    return __uint_as_float(((unsigned)u) << 16);
}
__device__ __forceinline__ void gload16(const ushort* g, ushort* l) {
    __builtin_amdgcn_global_load_lds((const __attribute__((address_space(1))) void*)g,
                                     (__attribute__((address_space(3))) void*)l, 16, 0, 0);
}

// ---------------------------------------------------------------------------
// bf16 MFMA GEMM, R20: BARRIER-FREE per-wave-tile design.
// Session-wide evidence: every barrier-per-step kernel is pinned at 55-75us
// regardless of work (big5 12GF == big5 24GF == 56us across 6 structural
// variants: depth, nt-stores, bytes, tile size, occupancy, K-stagger all
// NULL); barrier-free kernels (ln/prep/head) never show in top-5. m97's same
// loop at K=4096 stages 40B/cyc/CU vs our 8.6 -> path is capable; the
// per-step s_barrier couples all waves to the slowest load's TAIL latency
// each step, and at 8-16 steps nothing amortizes.
// Design: each wave owns a 64x64 output tile + private 16KB LDS slice
// (A/B x 2 bufs x 2KB). It stages its own operands (8 gload16/step), paces
// itself with per-wave vmcnt(8), and NEVER syncs with other waves. No
// s_barrier / __syncthreads anywhere. Block = 4 waves sharing an m-panel
// (consecutive n-tiles -> A L2-hot). Epilogue per-wave (same-wave DS ops are
// in-order). Accumulation order per element unchanged -> numerics identical.
// C[M,N] = A[M,K]bf16 @ Wt[N,K]^T (+ bias1[n] + prow[(m%9)*ldp+n]) -> bf16
// ---------------------------------------------------------------------------
__global__ __launch_bounds__(256, 2) void mgemm(
    const ushort* __restrict__ A, int lda,
    const ushort* __restrict__ Wt, int ldw,
    const float* __restrict__ bias1,
    const float* __restrict__ prow, int ldp,
    ushort* __restrict__ outB, int ldo, int K, int NT)
{
    __shared__ ushort smem[4][8192];       // 64KB: per-wave 16KB slice
    const int wv = threadIdx.x >> 6, lane = threadIdx.x & 63;
    ushort* wb = smem[wv];                 // this wave's private slice

    // ---- XCD-aware bijective remap of block id [T1, m204 formula] ----
    const int nwg = gridDim.x;
    const int flat = blockIdx.x;
    const int swq = nwg >> 3, swr = nwg & 7;
    const int xcd = flat & 7, posi = flat >> 3;
    const int btix = (xcd < swr ? xcd * (swq + 1) : swr * (swq + 1) + (xcd - swr) * swq) + posi;
    const int w = btix * 4 + wv;           // global wave-tile id
    const int mt = w / NT, nt = w - mt * NT;
    const int m0 = mt * 64, n0 = nt * 64;

    f32x4 acc[4][4];
#pragma unroll
    for (int i = 0; i < 4; i++)
#pragma unroll
        for (int j = 0; j < 4; j++) acc[i][j] = (f32x4){0.f, 0.f, 0.f, 0.f};

    const ushort* Ab = A + (size_t)m0 * lda;
    const ushort* Wb = Wt + (size_t)n0 * ldw;

    // 8 gload16 per stage (4 A chunks + 4 B chunks, 16 rows each)
    auto stage = [&](int b, int k0) {
#pragma unroll
        for (int c = 0; c < 4; c++) {
            int row = c * 16 + (lane >> 2), p = lane & 3;
            int q = (p - (row >> 1)) & 3;
            gload16(Ab + (size_t)row * lda + k0 + q * 8, wb + b * 2048 + c * 512);
        }
#pragma unroll
        for (int c = 0; c < 4; c++) {
            int row = c * 16 + (lane >> 2), p = lane & 3;
            int q = (p - (row >> 1)) & 3;
            gload16(Wb + (size_t)row * ldw + k0 + q * 8, wb + 4096 + b * 2048 + c * 512);
        }
    };

    const int nsteps = K >> 5;             // 8..32 at all call sites
    stage(0, 0);
    for (int s = 0; s < nsteps; s++) {
        if (s + 1 < nsteps) {
            stage((s + 1) & 1, (s + 1) << 5);                  // prefetch next
            asm volatile("s_waitcnt vmcnt(8)" ::: "memory");   // stage(s) done
        } else {
            asm volatile("s_waitcnt vmcnt(0)" ::: "memory");   // last stage done
        }
        const ushort* sA = wb + (s & 1) * 2048;
        const ushort* sB = wb + 4096 + (s & 1) * 2048;
        const int qg = lane >> 4;
        bf16x8 af[4], bfr[4];
#pragma unroll
        for (int bi = 0; bi < 4; bi++) {
            int r = bi * 16 + (lane & 15);
            af[bi] = *(const bf16x8*)(sA + (r * 4 + ((qg + (r >> 1)) & 3)) * 8);
        }
#pragma unroll
        for (int bj = 0; bj < 4; bj++) {
            int r = bj * 16 + (lane & 15);
            bfr[bj] = *(const bf16x8*)(sB + (r * 4 + ((qg + (r >> 1)) & 3)) * 8);
        }
        __builtin_amdgcn_s_setprio(1);
#pragma unroll
        for (int bi = 0; bi < 4; bi++)
#pragma unroll
            for (int bj = 0; bj < 4; bj++)
                acc[bi][bj] = __builtin_amdgcn_mfma_f32_16x16x32_bf16(
                    af[bi], bfr[bj], acc[bi][bj], 0, 0, 0);
        __builtin_amdgcn_s_setprio(0);
    }

    // ---- per-wave epilogue: (+prow/bias via LDS) + LDS-transpose store ----
    // Same-wave DS ops are in-order; compiler inserts lgkmcnt. No barriers.
    float* sP = (float*)wb;                // 9 x 64 f32 = 2304B (wb[0..1152))
    const bool haveP = (prow != 0);
    if (haveP) {
#pragma unroll
        for (int i = 0; i < 9; i++)
            sP[i * 64 + lane] = prow[(size_t)i * ldp + n0 + lane] + bias1[n0 + lane];
    }
    ushort* T = wb + 1280;                 // 64 x 68 ushorts = 8704B (ends 5632)
#pragma unroll
    for (int bi = 0; bi < 4; bi++) {
#pragma unroll
        for (int r = 0; r < 4; r++) {
            int row = bi * 16 + (lane >> 4) * 4 + r;
            int r9 = (m0 + row) % 9;
#pragma unroll
            for (int bj = 0; bj < 4; bj++) {
                int col = bj * 16 + (lane & 15);
                float v = acc[bi][bj][r];
                if (haveP) v += sP[r9 * 64 + col];
                T[row * 68 + col] = f2b(v);
            }
        }
    }
#pragma unroll
    for (int p4 = 0; p4 < 4; p4++) {
        int row = p4 * 16 + (lane >> 2), cq = (lane & 3) * 16;
        const ushort* src = T + row * 68 + cq;
        ushort* dst = outB + (size_t)(m0 + row) * ldo + n0 + cq;
        *(bf16x8*)dst = *(const bf16x8*)src;
        *(bf16x8*)(dst + 8) = *(const bf16x8*)(src + 8);
    }
}

// ---------------------------------------------------------------------------
// pjgemm: both projections in ONE dispatch. blockIdx.z selects the job
// (z=0: low K=512, z=1: high K=1024); full-K, bias epilogue, bf16 out.
// (128^2 tile, 3-buffer depth-2 — frozen; not in top-5.)
// ---------------------------------------------------------------------------
struct PJArg {
    const ushort* A[2];
    const ushort* W[2];
    const float*  bias[2];
    ushort*       out[2];
    int lda[2], K[2];
};

__global__ __launch_bounds__(256, 3) void pjgemm(PJArg pa)
{
    __shared__ ushort sA[3][128 * 32];
    __shared__ ushort sB[3][128 * 32];
    const int z = blockIdx.z;
    const ushort* __restrict__ A  = pa.A[z];
    const ushort* __restrict__ Wt = pa.W[z];
    const float*  __restrict__ bias = pa.bias[z];
    ushort* out = pa.out[z];
    const int lda = pa.lda[z], ldw = lda, K = pa.K[z];

    const int wv = threadIdx.x >> 6, lane = threadIdx.x & 63;
    const int rh = wv & 1, ch = wv >> 1;

    const int GX = gridDim.x;
    const int nwg = GX * gridDim.y;
    const int flat = blockIdx.y * GX + blockIdx.x;
    const int swq = nwg >> 3, swr = nwg & 7;
    const int xcd = flat & 7, posi = flat >> 3;
    const int tix = (xcd < swr ? xcd * (swq + 1) : swr * (swq + 1) + (xcd - swr) * swq) + posi;
    const int m0 = (tix / GX) * 128, n0 = (tix % GX) * 128;

    f32x4 acc[4][4];
#pragma unroll
    for (int i = 0; i < 4; i++)
#pragma unroll
        for (int j = 0; j < 4; j++) acc[i][j] = (f32x4){0.f, 0.f, 0.f, 0.f};

    const ushort* Ab = A + (size_t)m0 * lda;
    const ushort* Wb = Wt + (size_t)n0 * ldw;

    auto stage = [&](int b, int k0) {
#pragma unroll
        for (int i = 0; i < 2; i++) {
            int c = wv * 2 + i;
            int u = c * 64 + lane;
            int row = u >> 2, p = u & 3;
            int q = (p - (row >> 1)) & 3;
            gload16(Ab + (size_t)row * lda + k0 + q * 8, sA[b] + c * 512);
            gload16(Wb + (size_t)row * ldw + k0 + q * 8, sB[b] + c * 512);
        }
    };

    const int nsteps = K >> 5;       // 16 or 32
    stage(0, 0);
    stage(1, 32);
    int cur = 0;
    for (int s = 0; s < nsteps; s++) {
        if (s + 1 < nsteps) {
            asm volatile("s_waitcnt vmcnt(4)" ::: "memory");
        } else {
            asm volatile("s_waitcnt vmcnt(0)" ::: "memory");
        }
        __builtin_amdgcn_s_barrier();
        __builtin_amdgcn_sched_barrier(0);
        if (s + 2 < nsteps) {
            int nb = cur + 2; if (nb >= 3) nb -= 3;
            stage(nb, (s + 2) << 5);
        }

        const int qg = lane >> 4;
        bf16x8 af[4], bfr[4];
#pragma unroll
        for (int bi = 0; bi < 4; bi++) {
            int r = rh * 64 + bi * 16 + (lane & 15);
            af[bi] = *(const bf16x8*)(sA[cur] + (r * 4 + ((qg + (r >> 1)) & 3)) * 8);
        }
#pragma unroll
        for (int bj = 0; bj < 4; bj++) {
            int r = ch * 64 + bj * 16 + (lane & 15);
            bfr[bj] = *(const bf16x8*)(sB[cur] + (r * 4 + ((qg + (r >> 1)) & 3)) * 8);
        }
        __builtin_amdgcn_s_setprio(1);
#pragma unroll
        for (int bi = 0; bi < 4; bi++)
#pragma unroll
            for (int bj = 0; bj < 4; bj++)
                acc[bi][bj] = __builtin_amdgcn_mfma_f32_16x16x32_bf16(
                    af[bi], bfr[bj], acc[bi][bj], 0, 0, 0);
        __builtin_amdgcn_s_setprio(0);
        __builtin_amdgcn_sched_barrier(0);
        cur++; if (cur >= 3) cur -= 3;
    }

    // epilogue: + bias[n], write bf16
    float* sBias = (float*)sA;
    __syncthreads();
    if (threadIdx.x < 128) sBias[threadIdx.x] = bias[n0 + threadIdx.x];
    __syncthreads();

#pragma unroll
    for (int bi = 0; bi < 4; bi++) {
#pragma unroll
        for (int r = 0; r < 4; r++) {
            int m = m0 + rh * 64 + bi * 16 + (lane >> 4) * 4 + r;
#pragma unroll
            for (int bj = 0; bj < 4; bj++) {
                int nc = ch * 64 + bj * 16 + (lane & 15);
                float v = acc[bi][bj][r] + sBias[nc];
                out[(size_t)m * 512 + n0 + nc] = f2b(v);
            }
        }
    }
}

// ---------------------------------------------------------------------------
// weight transpose+convert: out[n*ldo + k] = bf16(src[(off0+k)*N + n])
// ---------------------------------------------------------------------------
#define NJOBS 16
struct TJobsArg {
    const float* src[NJOBS];
    long dst[NJOBS];
    int K[NJOBS], N[NJOBS], off0[NJOBS], ldo[NJOBS];
};

__global__ __launch_bounds__(256) void tw_kernel(TJobsArg ja, ushort* wbuf)
{
    int j = blockIdx.y;
    int K = ja.K[j], N = ja.N[j];
    int tk = K >> 5, tn = N >> 5;
    int t = blockIdx.x;
    if (t >= tk * tn) return;
    int kt = t % tk, nt = t / tk;
    const float* src = ja.src[j];
    ushort* out = wbuf + ja.dst[j];
    int ldo = ja.ldo[j];
    __shared__ float L[32][33];
    int r = threadIdx.x >> 5, c = threadIdx.x & 31;
#pragma unroll
    for (int rr = 0; rr < 4; rr++) {
        int k = kt * 32 + rr * 8 + r;
        L[rr * 8 + r][c] = src[(size_t)(ja.off0[j] + k) * N + nt * 32 + c];
    }
    __syncthreads();
#pragma unroll
    for (int rr = 0; rr < 4; rr++) {
        int n = nt * 32 + rr * 8 + r;
        out[(size_t)n * ldo + kt * 32 + c] = f2b(L[c][rr * 8 + r]);
    }
}

// ---------------------------------------------------------------------------
// Graph-per-block edge kernel, templated on O (compile-time strides).
// Two-phase staging: AdAs -> logits -> restage PdPs under softmax.
// PB row n: [Pd(O)|Ps(O)|Ad(O)|As(O)|skip(O)].
// ---------------------------------------------------------------------------
template<int O>
__global__ __launch_bounds__(256) void edge_kernel_t(
    const ushort* __restrict__ PB, const float* __restrict__ att2_w,
    ushort* __restrict__ Gout, int ldG, float* __restrict__ S)
{
    constexpr int O2 = O * 2, O5 = O * 5;
    constexpr int tpr = O >> 8;
    constexpr int tcount = 9 * tpr;
    constexpr int nch = O >> 3;
    constexpr int cshift = (O == 256) ? 5 : 6;
    constexpr int E = O >> 6;
    __shared__ ushort sPB[9 * O2];
    __shared__ float sAw[O];
    __shared__ float logits[72];
    __shared__ float aw[72];
    const int g = blockIdx.x;
    const int tid = threadIdx.x, lane = tid & 63, wave = tid >> 6;
    const ushort* gbase = PB + (size_t)g * 9 * O5;

    // phase A: stage Ad|As (cols [2O,4O) of each PB row)
    for (int i = wave; i < tcount; i += 4) {
        int row = i / tpr, co = i - row * tpr;
        gload16(gbase + (size_t)row * O5 + O2 + co * 512 + lane * 8, sPB + i * 512);
    }
    for (int c = tid; c < O; c += 256) sAw[c] = att2_w[c];
    __syncthreads();

    for (int e = wave; e < 72; e += 4) {
        int d = e >> 3, k = e & 7;
        int s = k + (k >= d);
        const ushort* ad = sPB + d * O2 + lane * E;
        const ushort* as = sPB + s * O2 + O + lane * E;
        const float* wp = sAw + lane * E;
        float p = 0.f;
        if constexpr (E == 4) {
            ushort4 a4 = *(const ushort4*)ad;
            ushort4 s4 = *(const ushort4*)as;
            float4 w4 = *(const float4*)wp;
            const ushort* ap = (const ushort*)&a4;
            const ushort* sp = (const ushort*)&s4;
            const float* wf = (const float*)&w4;
#pragma unroll
            for (int j = 0; j < 4; j++) {
                float v = b2f(ap[j]) + b2f(sp[j]);
                v = fmaxf(v, 0.01f * v);
                p += v * wf[j];
            }
        } else {
            bf16x8 a8 = *(const bf16x8*)ad;
            bf16x8 s8 = *(const bf16x8*)as;
            float4 w0 = *(const float4*)wp;
            float4 w1 = *(const float4*)(wp + 4);
            const ushort* ap = (const ushort*)&a8;
            const ushort* sp = (const ushort*)&s8;
            const float wf[8] = {w0.x, w0.y, w0.z, w0.w, w1.x, w1.y, w1.z, w1.w};
#pragma unroll
            for (int j = 0; j < 8; j++) {
                float v = b2f(ap[j]) + b2f(sp[j]);
                v = fmaxf(v, 0.01f * v);
                p += v * wf[j];
            }
        }
#pragma unroll
        for (int off = 32; off; off >>= 1) p += __shfl_down(p, off, 64);
        if (lane == 0) logits[e] = p;     // att2_b cancels in softmax
    }
    __syncthreads();                      // AdAs reads complete

    // phase B: restage Pd|Ps (cols [0,2O)) over the same buffer;
    // latency hides under softmax below.
    for (int i = wave; i < tcount; i += 4) {
        int row = i / tpr, co = i - row * tpr;
        gload16(gbase + (size_t)row * O5 + co * 512 + lane * 8, sPB + i * 512);
    }

    if (tid < 9) {
        float m = -INFINITY;
#pragma unroll
        for (int k = 0; k < 8; k++) m = fmaxf(m, logits[tid * 8 + k]);
        float s = 0.f, ee[8];
#pragma unroll
        for (int k = 0; k < 8; k++) { ee[k] = expf(logits[tid * 8 + k] - m); s += ee[k]; }
        float inv = 1.0f / (s + 1e-16f);
#pragma unroll
        for (int k = 0; k < 8; k++) aw[tid * 8 + k] = ee[k] * inv;
        S[g * 9 + tid] = s * inv;
    }
    __syncthreads();                      // drains vmcnt -> PdPs staged; aw ready

    for (int idx = tid; idx < 9 * nch; idx += 256) {
        int n = idx >> cshift, cc = idx & (nch - 1);
        bf16x8 pdv = *(const bf16x8*)(sPB + n * O2 + cc * 8);
        const ushort* pp = (const ushort*)&pdv;
        float pdf[8];
#pragma unroll
        for (int j = 0; j < 8; j++) pdf[j] = b2f(pp[j]);
        float acc8[8];
#pragma unroll
        for (int j = 0; j < 8; j++) acc8[j] = 0.f;
#pragma unroll
        for (int k = 0; k < 8; k++) {
            int s = k + (k >= n);
            float w = aw[n * 8 + k];
            bf16x8 psv = *(const bf16x8*)(sPB + s * O2 + O + cc * 8);
            const ushort* qp = (const ushort*)&psv;
#pragma unroll
            for (int j = 0; j < 8; j++)
                acc8[j] += w * gelu_fast(pdf[j] + b2f(qp[j]));
        }
        ushort o8[8];
#pragma unroll
        for (int j = 0; j < 8; j++) o8[j] = f2b(acc8[j]);
        *(bf16x8*)(Gout + (size_t)(g * 9 + n) * ldG + cc * 8) = *(const bf16x8*)o8;
    }
}

// ---------------------------------------------------------------------------
// Fused upd-epilogue + LayerNorm, wave-per-row, bf16 partials P0:
//   t = bf16(P0) + ub[c] + vb[c]*S[n] + posU[(n%9)*O+c];
//   h = gelu(t) + skip(bf16);  LN(h) -> outB bf16 (row remap) or outF fp32
// ---------------------------------------------------------------------------
__global__ __launch_bounds__(256) void ln_kernel(
    const ushort* __restrict__ P0,
    const float* __restrict__ ub, const float* __restrict__ vb,
    const float* __restrict__ S, const float* __restrict__ posU,
    const ushort* __restrict__ PBs, int ld5,
    const float* __restrict__ gw, const float* __restrict__ bw,
    ushort* outB, int ldoB, int rowsplit, float* outF, int O)
{
    const int wid = threadIdx.x >> 6, lane = threadIdx.x & 63;
    const int n = blockIdx.x * 4 + wid;
    const float sv = S[n];
    const ushort* p0 = P0 + (size_t)n * O;
    const ushort* sr = PBs + (size_t)n * ld5;
    const float* pu = posU + (size_t)(n % 9) * O;
    const int q = O >> 6;              // 4 or 8 elems per lane
    const int c0 = lane * q;

    float vals[8];
    float sum = 0.f;
    if (O == 256) {
        ushort4 pv = *(const ushort4*)(p0 + c0);
        ushort4 sk = *(const ushort4*)(sr + c0);
        float4 uu = *(const float4*)(ub + c0);
        float4 vv = *(const float4*)(vb + c0);
        float4 gg = *(const float4*)(pu + c0);
        const ushort tp[4] = {pv.x, pv.y, pv.z, pv.w};
        const ushort ts[4] = {sk.x, sk.y, sk.z, sk.w};
        const float tu[4] = {uu.x, uu.y, uu.z, uu.w};
        const float tv[4] = {vv.x, vv.y, vv.z, vv.w};
        const float tg[4] = {gg.x, gg.y, gg.z, gg.w};
#pragma unroll
        for (int j = 0; j < 4; j++) {
            float t = b2f(tp[j]) + tu[j] + tv[j] * sv + tg[j];
            vals[j] = gelu_f(t) + b2f(ts[j]);
            sum += vals[j];
        }
    } else {                           // O == 512
        bf16x8 pv = *(const bf16x8*)(p0 + c0);
        bf16x8 sk = *(const bf16x8*)(sr + c0);
        const ushort* tp = (const ushort*)&pv;
        const ushort* ts = (const ushort*)&sk;
        float4 u0 = *(const float4*)(ub + c0), u1 = *(const float4*)(ub + c0 + 4);
        float4 v0 = *(const float4*)(vb + c0), v1 = *(const float4*)(vb + c0 + 4);
        float4 g0 = *(const float4*)(pu + c0), g1 = *(const float4*)(pu + c0 + 4);
        const float tu[8] = {u0.x,u0.y,u0.z,u0.w, u1.x,u1.y,u1.z,u1.w};
        const float tv[8] = {v0.x,v0.y,v0.z,v0.w, v1.x,v1.y,v1.z,v1.w};
        const float tg[8] = {g0.x,g0.y,g0.z,g0.w, g1.x,g1.y,g1.z,g1.w};
#pragma unroll
        for (int j = 0; j < 8; j++) {
            float t = b2f(tp[j]) + tu[j] + tv[j] * sv + tg[j];
            vals[j] = gelu_f(t) + b2f(ts[j]);
            sum += vals[j];
        }
    }

#pragma unroll
    for (int off = 32; off; off >>= 1) sum += __shfl_xor(sum, off, 64);
    const float mu = sum / (float)O;
    float var = 0.f;
#pragma unroll
    for (int j = 0; j < 8; j++) {
        if (j < q) { float d = vals[j] - mu; var += d * d; }
    }
#pragma unroll
    for (int off = 32; off; off >>= 1) var += __shfl_xor(var, off, 64);
    const float rstd = rsqrtf(var / (float)O + 1e-5f);

    int orow = n, coloff = 0;
    if (n >= rowsplit) { orow = n - rowsplit; coloff = 256; }

    if (outB) {
        ushort o[8];
#pragma unroll
        for (int j = 0; j < 8; j++) {
            if (j < q) o[j] = f2b((vals[j] - mu) * rstd * gw[c0 + j] + bw[c0 + j]);
        }
        ushort* dst = outB + (size_t)orow * ldoB + coloff + c0;
        if (q == 4) *(ushort4*)dst = *(const ushort4*)o;
        else        *(bf16x8*)dst = *(const bf16x8*)o;
    }
    if (outF) {
        float* dst = outF + (size_t)n * O + c0;
#pragma unroll
        for (int j = 0; j < 8; j++) {
            if (j < q) dst[j] = (vals[j] - mu) * rstd * gw[c0 + j] + bw[c0 + j];
        }
    }
}

// ---------------------------------------------------------------------------
// prep: concat biases, pos tables (posPB/posU), vb, pw2 bf16 copies,
//       and feat_low/feat_high fp32->bf16 conversion (merged f2b)
// ---------------------------------------------------------------------------
__global__ void prep_kernel(
    const float* __restrict__ pw1_b1, const float* __restrict__ att1_b1, const float* __restrict__ skip_b1,
    const float* __restrict__ pw1_b2, const float* __restrict__ att1_b2, const float* __restrict__ skip_b2,
    const float* __restrict__ pos_table,
    const float* __restrict__ s1_pw1, const float* __restrict__ s1_att, const float* __restrict__ s1_skp,
    const float* __restrict__ s2_pw1, const float* __restrict__ s2_att, const float* __restrict__ s2_skp,
    const float* __restrict__ pw2_b1, const float* __restrict__ upd_w1,
    const float* __restrict__ pw2_b2, const float* __restrict__ upd_w2,
    const float* __restrict__ pw2_w1, const float* __restrict__ pw2_w2,
    const float* __restrict__ feat_low, const float* __restrict__ feat_high,
    float* biasC1, float* biasC2,
    float* posPB1, float* posPB2, float* posU1, float* posU2,
    float* vb1, float* vb2, ushort* pw2f1, ushort* pw2f2, ushort* featB)
{
    int i = blockIdx.x * 256 + threadIdx.x;
    if (i < 1280) {
        float v;
        if (i < 256) v = pw1_b1[i];
        else if (i < 512) v = 0.f;
        else if (i < 768) v = att1_b1[i - 512];
        else if (i < 1024) v = 0.f;
        else v = skip_b1[i - 1024];
        biasC1[i] = v;
        return;
    }
    i -= 1280;
    if (i < 2560) {
        float v;
        if (i < 512) v = pw1_b2[i];
        else if (i < 1024) v = 0.f;
        else if (i < 1536) v = att1_b2[i - 1024];
        else if (i < 2048) v = 0.f;
        else v = skip_b2[i - 2048];
        biasC2[i] = v;
        return;
    }
    i -= 2560;
    if (i < 9 * 1280) {   // posPB1[r][n]
        int r = i / 1280, n = i - r * 1280;
        int sec = n >> 8, c = n & 255;
        const float* src; int row0;
        if (sec == 0) { src = s1_pw1; row0 = 256; }
        else if (sec == 1) { src = s1_pw1; row0 = 576; }
        else if (sec == 2) { src = s1_att; row0 = 512; }
        else if (sec == 3) { src = s1_att; row0 = 576; }
        else { src = s1_skp; row0 = 256; }
        float a = 0.f;
        for (int k = 0; k < 64; k++) a += pos_table[r * 64 + k] * src[(size_t)(row0 + k) * 256 + c];
        posPB1[i] = a;
        return;
    }
    i -= 9 * 1280;
    if (i < 9 * 2560) {   // posPB2[r][n]
        int r = i / 2560, n = i - r * 2560;
        int sec = n >> 9, c = n & 511;
        const float* src; int row0;
        if (sec == 0) { src = s2_pw1; row0 = 512; }
        else if (sec == 1) { src = s2_pw1; row0 = 1088; }
        else if (sec == 2) { src = s2_att; row0 = 1024; }
        else if (sec == 3) { src = s2_att; row0 = 1088; }
        else { src = s2_skp; row0 = 512; }
        float a = 0.f;
        for (int k = 0; k < 64; k++) a += pos_table[r * 64 + k] * src[(size_t)(row0 + k) * 512 + c];
        posPB2[i] = a;
        return;
    }
    i -= 9 * 2560;
    if (i < 9 * 256) {    // posU1
        int r = i >> 8, c = i & 255;
        float a = 0.f;
        for (int k = 0; k < 64; k++) a += pos_table[r * 64 + k] * upd_w1[(size_t)(256 + k) * 256 + c];
        posU1[i] = a;
        return;
    }
    i -= 9 * 256;
    if (i < 9 * 512) {    // posU2
        int r = i >> 9, c = i & 511;
        float a = 0.f;
        for (int k = 0; k < 64; k++) a += pos_table[r * 64 + k] * upd_w2[(size_t)(512 + k) * 512 + c];
        posU2[i] = a;
        return;
    }
    i -= 9 * 512;
    if (i < 256) {        // vb1[n] = sum_j pw2_b1[j] * upd_w1[(320+j)][n]
        float a = 0.f;
        for (int j = 0; j < 256; j++) a += pw2_b1[j] * upd_w1[(size_t)(320 + j) * 256 + i];
        vb1[i] = a;
        return;
    }
    i -= 256;
    if (i < 512) {        // vb2
        float a = 0.f;
        for (int j = 0; j < 512; j++) a += pw2_b2[j] * upd_w2[(size_t)(576 + j) * 512 + i];
        vb2[i] = a;
        return;
    }
    i -= 512;
    if (i < 256 * 256) { pw2f1[i] = f2b(pw2_w1[i]); return; }
    i -= 256 * 256;
    if (i < 512 * 512) { pw2f2[i] = f2b(pw2_w2[i]); return; }
    i -= 512 * 512;
    if (i < NN * 512 / 4) {   // feat_low -> featB bf16
        float4 v = ((const float4*)feat_low)[i];
        ushort4 o;
        o.x = f2b(v.x); o.y = f2b(v.y); o.z = f2b(v.z); o.w = f2b(v.w);
        ((ushort4*)featB)[i] = o;
        return;
    }
    i -= NN * 512 / 4;
    if (i < NN * 1024 / 4) {  // feat_high -> featB + NN*512
        float4 v = ((const float4*)feat_high)[i];
        ushort4 o;
        o.x = f2b(v.x); o.y = f2b(v.y); o.z = f2b(v.z); o.w = f2b(v.w);
        ((ushort4*)(featB + (size_t)NN * 512))[i] = o;
    }
}

// ---------------------------------------------------------------------------
// head: pool(9 rows) + cls1 (gelu) + cls2, 4 graphs per block
// ---------------------------------------------------------------------------
__global__ __launch_bounds__(256) void head_kernel(
    const float* __restrict__ h2,
    const float* __restrict__ cls1_w, const float* __restrict__ cls1_b,
    const float* __restrict__ cls2_w, const float* __restrict__ cls2_b,
    float* __restrict__ out)
{
    __shared__ float pooled[4][512];
    __shared__ float hid[4][256];
    const int b = blockIdx.x, tid = threadIdx.x;

    for (int idx = tid; idx < 4 * 512; idx += 256) {
        int gi = idx >> 9, c = idx & 511;
        const float* base = h2 + (size_t)((b * 4 + gi) * 9) * 512 + c;
        float s = 0.f;
#pragma unroll
        for (int k = 0; k < NPG; k++) s += base[(size_t)k * 512];
        pooled[gi][c] = s;
    }
    __syncthreads();

    {
        float acc[4] = {0.f, 0.f, 0.f, 0.f};
        for (int c = 0; c < 512; c++) {
            float w = cls1_w[(size_t)c * 256 + tid];
#pragma unroll
            for (int gi = 0; gi < 4; gi++) acc[gi] += pooled[gi][c] * w;
        }
        float bb = cls1_b[tid];
#pragma unroll
        for (int gi = 0; gi < 4; gi++) hid[gi][tid] = gelu_f(acc[gi] + bb);
    }
    __syncthreads();

    {
        int gi = tid >> 6, lane = tid & 63;
        float p = 0.f;
#pragma unroll
        for (int i = 0; i < 4; i++) p += hid[gi][lane + 64 * i] * cls2_w[lane + 64 * i];
#pragma unroll
        for (int off = 32; off; off >>= 1) p += __shfl_down(p, off, 64);
        if (lane == 0) out[b * 4 + gi] = p + cls2_b[0];
    }
}

// ---------------------------------------------------------------------------
// Host side
// ---------------------------------------------------------------------------
static inline void mg(hipStream_t st, int M, int N, int K,
                      const ushort* A, int lda, const ushort* Wt, int ldw,
                      const float* bias1, const float* prow, int ldp,
                      ushort* outB, int ldo)
{
    int NT = N / 64;
    int nblk = (M / 64) * NT / 4;          // 4 wave-tiles per block
    mgemm<<<dim3(nblk), dim3(256), 0, st>>>(A, lda, Wt, ldw, bias1, prow, ldp,
                                            outB, ldo, K, NT);
}

extern "C" void kernel_launch(void* const* d_in, const int* in_sizes, int n_in,
                              void* d_out, int out_size, void* d_ws, size_t ws_size,
                              hipStream_t stream)
{
    (void)in_sizes; (void)n_in; (void)out_size; (void)ws_size;
    const float* feat_low   = (const float*)d_in[0];
    const float* feat_high  = (const float*)d_in[1];
    const float* pos_table  = (const float*)d_in[4];
    const float* proj_low_w  = (const float*)d_in[5];
    const float* proj_low_b  = (const float*)d_in[6];
    const float* proj_high_w = (const float*)d_in[7];
    const float* proj_high_b = (const float*)d_in[8];
    const float* cls1_w = (const float*)d_in[37];
    const float* cls1_b = (const float*)d_in[38];
    const float* cls2_w = (const float*)d_in[39];
    const float* cls2_b = (const float*)d_in[40];
    float* out = (float*)d_out;

    const float* s1_pw1 = (const float*)d_in[9];
    const float* s1_att = (const float*)d_in[13];
    const float* s1_upd = (const float*)d_in[17];
    const float* s1_skp = (const float*)d_in[21];
    const float* s2_pw1 = (const float*)d_in[23];
    const float* s2_att = (const float*)d_in[27];
    const float* s2_upd = (const float*)d_in[31];
    const float* s2_skp = (const float*)d_in[35];

    const float* att2_w1 = (const float*)d_in[15];
    const float* upd_b1  = (const float*)d_in[18];
    const float* ln_g1   = (const float*)d_in[19];
    const float* ln_b1   = (const float*)d_in[20];
    const float* att2_w2 = (const float*)d_in[29];
    const float* upd_b2  = (const float*)d_in[32];
    const float* ln_g2   = (const float*)d_in[33];
    const float* ln_b2   = (const float*)d_in[34];

    // ---- workspace layout (256B aligned) ----
    char* base = (char*)d_ws;
    size_t cur = 0;
    auto alloc = [&](size_t bytes) { void* p = base + cur; cur += (bytes + 255) & ~(size_t)255; return p; };
    void*   PBreg = alloc((size_t)NN * 2560 * 2);   // PB (s1: 18432x1280, s2: 9216x2560); featB alias
    ushort* PB    = (ushort*)PBreg;
    ushort* featB = (ushort*)PBreg;
    void*   IX1reg = alloc((size_t)NN2 * 512 * 2);  // ixa1 bf16; h2 fp32 alias (disjoint in time)
    ushort* ixa1  = (ushort*)IX1reg;
    float*  h2    = (float*)IX1reg;
    ushort* ixa2  = (ushort*)alloc((size_t)NN * 1024 * 2);
    ushort* PT    = (ushort*)alloc((size_t)NN2 * 512 * 2);  // upd bf16 partials
    float*  S     = (float*)alloc((size_t)NN2 * 4);
    float*  biasC1 = (float*)alloc(1280 * 4);
    float*  biasC2 = (float*)alloc(2560 * 4);
    float*  posPB1 = (float*)alloc(9 * 1280 * 4);
    float*  posPB2 = (float*)alloc(9 * 2560 * 4);
    float*  posU1  = (float*)alloc(9 * 256 * 4);
    float*  posU2  = (float*)alloc(9 * 512 * 4);
    float*  vb1   = (float*)alloc(256 * 4);
    float*  vb2   = (float*)alloc(512 * 4);
    ushort* wbuf  = (ushort*)alloc((size_t)3400000 * 2);

    // ---- weight transpose jobs (x-parts only; pos handled via prow tables) ----
    TJobsArg ja;
    long woff[16];
    {
        struct J { const float* s; int K, N, off0, ldo; long sz; };
        J js[NJOBS] = {
            {proj_low_w,  512, 256, 0, 512, 512L * 256},     // 0 projL
            {proj_high_w, 1024, 256, 0, 1024, 1024L * 256},  // 1 projH
            {s1_pw1, 256, 256, 0, 256, 256L * 256},          // 2 big5-1: pw1d
            {s1_pw1, 256, 256, 320, 256, 256L * 256},        // 3 pw1s
            {s1_att, 256, 256, 0, 256, 256L * 256},          // 4 attd
            {s1_att, 256, 256, 256, 256, 256L * 256},        // 5 atts
            {s1_skp, 256, 256, 0, 256, 256L * 256},          // 6 skip
            {s1_upd, 256, 256, 0, 512, 512L * 256},          // 7 updW1 (x cols)
            {s1_upd, 256, 256, 320, 256, 256L * 256},        // 8 updbT1 (aggr rows)
            {s2_pw1, 512, 512, 0, 512, 512L * 512},          // 9 big5-2: pw1d
            {s2_pw1, 512, 512, 576, 512, 512L * 512},        // 10 pw1s
            {s2_att, 512, 512, 0, 512, 512L * 512},          // 11 attd
            {s2_att, 512, 512, 512, 512, 512L * 512},        // 12 atts
            {s2_skp, 512, 512, 0, 512, 512L * 512},          // 13 skip
            {s2_upd, 512, 512, 0, 1024, 1024L * 512},        // 14 updW2 (x cols)
            {s2_upd, 512, 512, 576, 512, 512L * 512},        // 15 updbT2
        };
        long off = 0;
        for (int i = 0; i < NJOBS; i++) {
            ja.src[i] = js[i].s; ja.K[i] = js[i].K; ja.N[i] = js[i].N;
            ja.off0[i] = js[i].off0; ja.ldo[i] = js[i].ldo;
            ja.dst[i] = off; woff[i] = off;
            off += js[i].sz;
        }
    }
    long pw2off1 = woff[15] + 512L * 512;
    long pw2off2 = pw2off1 + 256L * 256;
    tw_kernel<<<dim3(256, NJOBS), dim3(256), 0, stream>>>(ja, wbuf);

    ushort* wBig5_1 = wbuf + woff[2];
    ushort* updW1   = wbuf + woff[7];
    ushort* updbT1  = wbuf + woff[8];
    ushort* wBig5_2 = wbuf + woff[9];
    ushort* updW2   = wbuf + woff[14];
    ushort* updbT2  = wbuf + woff[15];
    ushort* pw2f1   = wbuf + pw2off1;
    ushort* pw2f2   = wbuf + pw2off2;

    // ---- prep (biases, pos tables, vb, pw2 bf16, feat->bf16) ----
    {
        long tot = 1280 + 2560 + 9 * 1280 + 9 * 2560 + 9 * 256 + 9 * 512
                 + 256 + 512 + 256 * 256 + 512 * 512
                 + (long)NN * 512 / 4 + (long)NN * 1024 / 4;
        prep_kernel<<<dim3((unsigned)((tot + 255) / 256)), dim3(256), 0, stream>>>(
            (const float*)d_in[10], (const float*)d_in[14], (const float*)d_in[22],
            (const float*)d_in[24], (const float*)d_in[28], (const float*)d_in[36],
            pos_table,
            s1_pw1, s1_att, s1_skp, s2_pw1, s2_att, s2_skp,
            (const float*)d_in[12], s1_upd, (const float*)d_in[26], s2_upd,
            (const float*)d_in[11], (const float*)d_in[25],
            feat_low, feat_high,
            biasC1, biasC2, posPB1, posPB2, posU1, posU2, vb1, vb2, pw2f1, pw2f2, featB);
    }

    // ---- Wcomb = pw2 @ updb, transposed into updW G-columns ----
    mg(stream, 256, 256, 256, updbT1, 256, pw2f1, 256, 0, 0, 0, updW1 + 256, 512);
    mg(stream, 512, 512, 512, updbT2, 512, pw2f2, 512, 0, 0, 0, updW2 + 512, 1024);

    // ---- projections: ONE fused dispatch, full-K, direct bf16 + bias ----
    {
        PJArg pa;
        pa.A[0] = featB;                      pa.lda[0] = 512;  pa.K[0] = 512;
        pa.A[1] = featB + (size_t)NN * 512;   pa.lda[1] = 1024; pa.K[1] = 1024;
        pa.W[0] = wbuf + woff[0];
        pa.W[1] = wbuf + woff[1];
        pa.bias[0] = proj_low_b;
        pa.bias[1] = proj_high_b;
        pa.out[0] = ixa1;
        pa.out[1] = ixa1 + (size_t)NN * 512;
        pjgemm<<<dim3(2, NN / 128, 2), dim3(256), 0, stream>>>(pa);
    }

    // ---- stage 1 (batched, M = 18432) ----
    mg(stream, NN2, 1280, 256, ixa1, 512, wBig5_1, 256, biasC1, posPB1, 1280, PB, 1280);
    edge_kernel_t<256><<<dim3(2 * NUM_GRAPHS), dim3(256), 0, stream>>>(
        PB, att2_w1, ixa1 + 256, 512, S);
    mg(stream, NN2, 256, 512, ixa1, 512, updW1, 512, 0, 0, 0, PT, 256);
    ln_kernel<<<dim3(NN2 / 4), dim3(256), 0, stream>>>(
        PT, upd_b1, vb1, S, posU1,
        PB + 4 * 256, 1280, ln_g1, ln_b1, ixa2, 1024, NN, 0, 256);

    // ---- stage 2 ----
    mg(stream, NN, 2560, 512, ixa2, 1024, wBig5_2, 512, biasC2, posPB2, 2560, PB, 2560);
    edge_kernel_t<512><<<dim3(NUM_GRAPHS), dim3(256), 0, stream>>>(
        PB, att2_w2, ixa2 + 512, 1024, S);
    mg(stream, NN, 512, 1024, ixa2, 1024, updW2, 1024, 0, 0, 0, PT, 512);
    ln_kernel<<<dim3(NN / 4), dim3(256), 0, stream>>>(
        PT, upd_b2, vb2, S, posU2,
        PB + 4 * 512, 2560, ln_g2, ln_b2, 0, 0, 1 << 30, h2, 512);

    // ---- head ----
    head_kernel<<<dim3(NUM_GRAPHS / 4), dim3(256), 0, stream>>>(h2, cls1_w, cls1_b, cls2_w, cls2_b, out);
}

// Round 12
// 518.713 us; speedup vs baseline: 1.0444x; 1.0321x over previous
//
#include <hip/hip_runtime.h>
#include <math.h>

// ---------- model constants ----------
#define NUM_GRAPHS 1024
#define NPG 9
#define NN 9216            // nodes
#define NN2 18432          // batched stage-1 rows (low|high)
#define POSD 64

typedef __attribute__((ext_vector_type(8))) short bf16x8;
typedef __attribute__((ext_vector_type(4))) float f32x4;

__device__ __forceinline__ float gelu_f(float x) {
    return 0.5f * x * (1.0f + erff(x * 0.70710678118654752f));
}
// fast gelu: x*sigmoid(2y) == 0.5x(1+tanh(y)) algebraically (edge aggr only)
__device__ __forceinline__ float gelu_fast(float x) {
    float y2 = 1.5957691216f * x * (1.0f + 0.044715f * x * x);  // 2*sqrt(2/pi)*...
    float t = __expf(fminf(y2, 80.f));
    return x * t * __frcp_rn(t + 1.0f);
}
__device__ __forceinline__ ushort f2b(float v) {
    unsigned u = __float_as_uint(v);
    return (ushort)((u + 0x7fffu + ((u >> 16) & 1u)) >> 16);
}
__device__ __forceinline__ float b2f(ushort u) {
    return __uint_as_float(((unsigned)u) << 16);
}
__device__ __forceinline__ void gload16(const ushort* g, ushort* l) {
    __builtin_amdgcn_global_load_lds((const __attribute__((address_space(1))) void*)g,
                                     (__attribute__((address_space(3))) void*)l, 16, 0, 0);
}

// ---------------------------------------------------------------------------
// bf16 MFMA GEMM — R21: exact revert to the R8 configuration (session best,
// 527.0us). R18 (256x128), R19 (K-stagger), R20 (barrier-free) all regressed
// and are dropped; their theories are logged as falsified. The ~56us floor is
// invariant to 7 structural levers; this kernel family is at its plateau.
// R4 K-loop: triple-buffer depth-2 prefetch, counted vmcnt, one barrier/step.
// R16 epilogue: coalesced LDS-transpose store.
// C[M,N] = A[M,K]bf16 @ Wt[N,K]^T (+ bias1[n] + prow[(m%9)*ldp+n]) -> bf16
// Tile 128x128, 4 waves, BK=32, LDS 48KB -> 3 blocks/CU.
// ---------------------------------------------------------------------------
__global__ __launch_bounds__(256, 3) void mgemm(
    const ushort* __restrict__ A, int lda,
    const ushort* __restrict__ Wt, int ldw,
    const float* __restrict__ bias1,
    const float* __restrict__ prow, int ldp,
    ushort* __restrict__ outB, int ldo, int K)
{
    __shared__ ushort smem[24576];         // 48KB: sA = [0,12288), sB = [12288,24576)
    const int wv = threadIdx.x >> 6, lane = threadIdx.x & 63;
    const int rh = wv & 1, ch = wv >> 1;

    // ---- XCD-aware bijective remap of (bx,by) [T1, m204 formula] ----
    const int GX = gridDim.x;
    const int nwg = GX * gridDim.y;
    const int flat = blockIdx.y * GX + blockIdx.x;
    const int swq = nwg >> 3, swr = nwg & 7;
    const int xcd = flat & 7, posi = flat >> 3;
    const int tix = (xcd < swr ? xcd * (swq + 1) : swr * (swq + 1) + (xcd - swr) * swq) + posi;
    const int m0 = (tix / GX) * 128, n0 = (tix % GX) * 128;

    f32x4 acc[4][4];
#pragma unroll
    for (int i = 0; i < 4; i++)
#pragma unroll
        for (int j = 0; j < 4; j++) acc[i][j] = (f32x4){0.f, 0.f, 0.f, 0.f};

    const ushort* Ab = A + (size_t)m0 * lda;
    const ushort* Wb = Wt + (size_t)n0 * ldw;

    // 4 gload_lds instructions per wave per call -> 4 vmcnt slots per stage
    auto stage = [&](int b, int k0) {
        ushort* sA = smem + b * 4096;
        ushort* sB = smem + 12288 + b * 4096;
#pragma unroll
        for (int i = 0; i < 2; i++) {
            int c = wv * 2 + i;
            int u = c * 64 + lane;
            int row = u >> 2, p = u & 3;
            int q = (p - (row >> 1)) & 3;
            gload16(Ab + (size_t)row * lda + k0 + q * 8, sA + c * 512);
            gload16(Wb + (size_t)row * ldw + k0 + q * 8, sB + c * 512);
        }
    };

    const int nsteps = K >> 5;             // 8..16 at all call sites (>= 3)
    stage(0, 0);
    stage(1, 32);
    int cur = 0;
    for (int s = 0; s < nsteps; s++) {
        if (s + 1 < nsteps) {
            asm volatile("s_waitcnt vmcnt(4)" ::: "memory");   // stage(s) done
        } else {
            asm volatile("s_waitcnt vmcnt(0)" ::: "memory");   // last stage done
        }
        __builtin_amdgcn_s_barrier();      // all waves' stage(s) visible;
                                           // also: all step-(s-1) reads done
        __builtin_amdgcn_sched_barrier(0);
        if (s + 2 < nsteps) {
            int nb = cur + 2; if (nb >= 3) nb -= 3;
            stage(nb, (s + 2) << 5);       // writes buf((s-1)%3): safe
        }

        const ushort* sA = smem + cur * 4096;
        const ushort* sB = smem + 12288 + cur * 4096;
        const int qg = lane >> 4;
        bf16x8 af[4], bfr[4];
#pragma unroll
        for (int bi = 0; bi < 4; bi++) {
            int r = rh * 64 + bi * 16 + (lane & 15);
            af[bi] = *(const bf16x8*)(sA + (r * 4 + ((qg + (r >> 1)) & 3)) * 8);
        }
#pragma unroll
        for (int bj = 0; bj < 4; bj++) {
            int r = ch * 64 + bj * 16 + (lane & 15);
            bfr[bj] = *(const bf16x8*)(sB + (r * 4 + ((qg + (r >> 1)) & 3)) * 8);
        }
        __builtin_amdgcn_s_setprio(1);
#pragma unroll
        for (int bi = 0; bi < 4; bi++)
#pragma unroll
            for (int bj = 0; bj < 4; bj++)
                acc[bi][bj] = __builtin_amdgcn_mfma_f32_16x16x32_bf16(
                    af[bi], bfr[bj], acc[bi][bj], 0, 0, 0);
        __builtin_amdgcn_s_setprio(0);
        __builtin_amdgcn_sched_barrier(0);
        cur++; if (cur >= 3) cur -= 3;
    }

    // ---- epilogue: (+prow/bias via LDS) then LDS-transpose coalesced store
    __syncthreads();                       // K-loop LDS dead
    float* sP = (float*)smem;              // 9 x 129 floats = 4644B (< 8KB)
    const bool haveP = (prow != 0);
    if (haveP) {
        for (int i = threadIdx.x; i < 9 * 128; i += 256) {
            int rr = i >> 7, c = i & 127;
            sP[rr * 129 + c] = prow[(size_t)rr * ldp + n0 + c] + bias1[n0 + c];
        }
        __syncthreads();
    }
    ushort* T = smem + 4096;               // 128 x 136 ushort = 34.8KB (ends 21504 < 24576)
#pragma unroll
    for (int bi = 0; bi < 4; bi++) {
#pragma unroll
        for (int r = 0; r < 4; r++) {
            int row = rh * 64 + bi * 16 + (lane >> 4) * 4 + r;
            int r9 = (m0 + row) % 9;
#pragma unroll
            for (int bj = 0; bj < 4; bj++) {
                int col = ch * 64 + bj * 16 + (lane & 15);
                float v = acc[bi][bj][r];
                if (haveP) v += sP[r9 * 129 + col];
                T[row * 136 + col] = f2b(v);
            }
        }
    }
    __syncthreads();
    {
        int row = threadIdx.x >> 1, half = threadIdx.x & 1;
        const ushort* src = T + row * 136 + half * 64;
        ushort* dst = outB + (size_t)(m0 + row) * ldo + n0 + half * 64;
#pragma unroll
        for (int j = 0; j < 8; j++)
            *(bf16x8*)(dst + j * 8) = *(const bf16x8*)(src + j * 8);
    }
}

// ---------------------------------------------------------------------------
// pjgemm: both projections in ONE dispatch. blockIdx.z selects the job
// (z=0: low K=512, z=1: high K=1024); full-K, bias epilogue, bf16 out.
// ---------------------------------------------------------------------------
struct PJArg {
    const ushort* A[2];
    const ushort* W[2];
    const float*  bias[2];
    ushort*       out[2];
    int lda[2], K[2];
};

__global__ __launch_bounds__(256, 3) void pjgemm(PJArg pa)
{
    __shared__ ushort sA[3][128 * 32];
    __shared__ ushort sB[3][128 * 32];
    const int z = blockIdx.z;
    const ushort* __restrict__ A  = pa.A[z];
    const ushort* __restrict__ Wt = pa.W[z];
    const float*  __restrict__ bias = pa.bias[z];
    ushort* out = pa.out[z];
    const int lda = pa.lda[z], ldw = lda, K = pa.K[z];

    const int wv = threadIdx.x >> 6, lane = threadIdx.x & 63;
    const int rh = wv & 1, ch = wv >> 1;

    const int GX = gridDim.x;
    const int nwg = GX * gridDim.y;
    const int flat = blockIdx.y * GX + blockIdx.x;
    const int swq = nwg >> 3, swr = nwg & 7;
    const int xcd = flat & 7, posi = flat >> 3;
    const int tix = (xcd < swr ? xcd * (swq + 1) : swr * (swq + 1) + (xcd - swr) * swq) + posi;
    const int m0 = (tix / GX) * 128, n0 = (tix % GX) * 128;

    f32x4 acc[4][4];
#pragma unroll
    for (int i = 0; i < 4; i++)
#pragma unroll
        for (int j = 0; j < 4; j++) acc[i][j] = (f32x4){0.f, 0.f, 0.f, 0.f};

    const ushort* Ab = A + (size_t)m0 * lda;
    const ushort* Wb = Wt + (size_t)n0 * ldw;

    auto stage = [&](int b, int k0) {
#pragma unroll
        for (int i = 0; i < 2; i++) {
            int c = wv * 2 + i;
            int u = c * 64 + lane;
            int row = u >> 2, p = u & 3;
            int q = (p - (row >> 1)) & 3;
            gload16(Ab + (size_t)row * lda + k0 + q * 8, sA[b] + c * 512);
            gload16(Wb + (size_t)row * ldw + k0 + q * 8, sB[b] + c * 512);
        }
    };

    const int nsteps = K >> 5;       // 16 or 32
    stage(0, 0);
    stage(1, 32);
    int cur = 0;
    for (int s = 0; s < nsteps; s++) {
        if (s + 1 < nsteps) {
            asm volatile("s_waitcnt vmcnt(4)" ::: "memory");
        } else {
            asm volatile("s_waitcnt vmcnt(0)" ::: "memory");
        }
        __builtin_amdgcn_s_barrier();
        __builtin_amdgcn_sched_barrier(0);
        if (s + 2 < nsteps) {
            int nb = cur + 2; if (nb >= 3) nb -= 3;
            stage(nb, (s + 2) << 5);
        }

        const int qg = lane >> 4;
        bf16x8 af[4], bfr[4];
#pragma unroll
        for (int bi = 0; bi < 4; bi++) {
            int r = rh * 64 + bi * 16 + (lane & 15);
            af[bi] = *(const bf16x8*)(sA[cur] + (r * 4 + ((qg + (r >> 1)) & 3)) * 8);
        }
#pragma unroll
        for (int bj = 0; bj < 4; bj++) {
            int r = ch * 64 + bj * 16 + (lane & 15);
            bfr[bj] = *(const bf16x8*)(sB[cur] + (r * 4 + ((qg + (r >> 1)) & 3)) * 8);
        }
        __builtin_amdgcn_s_setprio(1);
#pragma unroll
        for (int bi = 0; bi < 4; bi++)
#pragma unroll
            for (int bj = 0; bj < 4; bj++)
                acc[bi][bj] = __builtin_amdgcn_mfma_f32_16x16x32_bf16(
                    af[bi], bfr[bj], acc[bi][bj], 0, 0, 0);
        __builtin_amdgcn_s_setprio(0);
        __builtin_amdgcn_sched_barrier(0);
        cur++; if (cur >= 3) cur -= 3;
    }

    // epilogue: + bias[n], write bf16
    float* sBias = (float*)sA;
    __syncthreads();
    if (threadIdx.x < 128) sBias[threadIdx.x] = bias[n0 + threadIdx.x];
    __syncthreads();

#pragma unroll
    for (int bi = 0; bi < 4; bi++) {
#pragma unroll
        for (int r = 0; r < 4; r++) {
            int m = m0 + rh * 64 + bi * 16 + (lane >> 4) * 4 + r;
#pragma unroll
            for (int bj = 0; bj < 4; bj++) {
                int nc = ch * 64 + bj * 16 + (lane & 15);
                float v = acc[bi][bj][r] + sBias[nc];
                out[(size_t)m * 512 + n0 + nc] = f2b(v);
            }
        }
    }
}

// ---------------------------------------------------------------------------
// weight transpose+convert: out[n*ldo + k] = bf16(src[(off0+k)*N + n])
// ---------------------------------------------------------------------------
#define NJOBS 16
struct TJobsArg {
    const float* src[NJOBS];
    long dst[NJOBS];
    int K[NJOBS], N[NJOBS], off0[NJOBS], ldo[NJOBS];
};

__global__ __launch_bounds__(256) void tw_kernel(TJobsArg ja, ushort* wbuf)
{
    int j = blockIdx.y;
    int K = ja.K[j], N = ja.N[j];
    int tk = K >> 5, tn = N >> 5;
    int t = blockIdx.x;
    if (t >= tk * tn) return;
    int kt = t % tk, nt = t / tk;
    const float* src = ja.src[j];
    ushort* out = wbuf + ja.dst[j];
    int ldo = ja.ldo[j];
    __shared__ float L[32][33];
    int r = threadIdx.x >> 5, c = threadIdx.x & 31;
#pragma unroll
    for (int rr = 0; rr < 4; rr++) {
        int k = kt * 32 + rr * 8 + r;
        L[rr * 8 + r][c] = src[(size_t)(ja.off0[j] + k) * N + nt * 32 + c];
    }
    __syncthreads();
#pragma unroll
    for (int rr = 0; rr < 4; rr++) {
        int n = nt * 32 + rr * 8 + r;
        out[(size_t)n * ldo + kt * 32 + c] = f2b(L[c][rr * 8 + r]);
    }
}

// ---------------------------------------------------------------------------
// Graph-per-block edge kernel, templated on O (compile-time strides ->
// shifts not v_mul_lo; logits phase = one-shot per-lane vector read).
// Two-phase staging: AdAs -> logits -> restage PdPs under softmax.
// PB row n: [Pd(O)|Ps(O)|Ad(O)|As(O)|skip(O)].
// ---------------------------------------------------------------------------
template<int O>
__global__ __launch_bounds__(256) void edge_kernel_t(
    const ushort* __restrict__ PB, const float* __restrict__ att2_w,
    ushort* __restrict__ Gout, int ldG, float* __restrict__ S)
{
    constexpr int O2 = O * 2, O5 = O * 5;
    constexpr int tpr = O >> 8;        // 512-ushort tiles per 2*O row chunk (1 or 2)
    constexpr int tcount = 9 * tpr;
    constexpr int nch = O >> 3;
    constexpr int cshift = (O == 256) ? 5 : 6;
    constexpr int E = O >> 6;          // channels per lane in logits (4 or 8)
    __shared__ ushort sPB[9 * O2];
    __shared__ float sAw[O];
    __shared__ float logits[72];
    __shared__ float aw[72];
    const int g = blockIdx.x;
    const int tid = threadIdx.x, lane = tid & 63, wave = tid >> 6;
    const ushort* gbase = PB + (size_t)g * 9 * O5;

    // phase A: stage Ad|As (cols [2O,4O) of each PB row)
    for (int i = wave; i < tcount; i += 4) {
        int row = i / tpr, co = i - row * tpr;
        gload16(gbase + (size_t)row * O5 + O2 + co * 512 + lane * 8, sPB + i * 512);
    }
    for (int c = tid; c < O; c += 256) sAw[c] = att2_w[c];
    __syncthreads();

    for (int e = wave; e < 72; e += 4) {
        int d = e >> 3, k = e & 7;
        int s = k + (k >= d);
        const ushort* ad = sPB + d * O2 + lane * E;
        const ushort* as = sPB + s * O2 + O + lane * E;
        const float* wp = sAw + lane * E;
        float p = 0.f;
        if constexpr (E == 4) {
            ushort4 a4 = *(const ushort4*)ad;
            ushort4 s4 = *(const ushort4*)as;
            float4 w4 = *(const float4*)wp;
            const ushort* ap = (const ushort*)&a4;
            const ushort* sp = (const ushort*)&s4;
            const float* wf = (const float*)&w4;
#pragma unroll
            for (int j = 0; j < 4; j++) {
                float v = b2f(ap[j]) + b2f(sp[j]);
                v = fmaxf(v, 0.01f * v);
                p += v * wf[j];
            }
        } else {
            bf16x8 a8 = *(const bf16x8*)ad;
            bf16x8 s8 = *(const bf16x8*)as;
            float4 w0 = *(const float4*)wp;
            float4 w1 = *(const float4*)(wp + 4);
            const ushort* ap = (const ushort*)&a8;
            const ushort* sp = (const ushort*)&s8;
            const float wf[8] = {w0.x, w0.y, w0.z, w0.w, w1.x, w1.y, w1.z, w1.w};
#pragma unroll
            for (int j = 0; j < 8; j++) {
                float v = b2f(ap[j]) + b2f(sp[j]);
                v = fmaxf(v, 0.01f * v);
                p += v * wf[j];
            }
        }
#pragma unroll
        for (int off = 32; off; off >>= 1) p += __shfl_down(p, off, 64);
        if (lane == 0) logits[e] = p;     // att2_b cancels in softmax
    }
    __syncthreads();                      // AdAs reads complete

    // phase B: restage Pd|Ps (cols [0,2O)) over the same buffer;
    // latency hides under softmax below.
    for (int i = wave; i < tcount; i += 4) {
        int row = i / tpr, co = i - row * tpr;
        gload16(gbase + (size_t)row * O5 + co * 512 + lane * 8, sPB + i * 512);
    }

    if (tid < 9) {
        float m = -INFINITY;
#pragma unroll
        for (int k = 0; k < 8; k++) m = fmaxf(m, logits[tid * 8 + k]);
        float s = 0.f, ee[8];
#pragma unroll
        for (int k = 0; k < 8; k++) { ee[k] = expf(logits[tid * 8 + k] - m); s += ee[k]; }
        float inv = 1.0f / (s + 1e-16f);
#pragma unroll
        for (int k = 0; k < 8; k++) aw[tid * 8 + k] = ee[k] * inv;
        S[g * 9 + tid] = s * inv;
    }
    __syncthreads();                      // drains vmcnt -> PdPs staged; aw ready

    for (int idx = tid; idx < 9 * nch; idx += 256) {
        int n = idx >> cshift, cc = idx & (nch - 1);
        bf16x8 pdv = *(const bf16x8*)(sPB + n * O2 + cc * 8);
        const ushort* pp = (const ushort*)&pdv;
        float pdf[8];
#pragma unroll
        for (int j = 0; j < 8; j++) pdf[j] = b2f(pp[j]);
        float acc8[8];
#pragma unroll
        for (int j = 0; j < 8; j++) acc8[j] = 0.f;
#pragma unroll
        for (int k = 0; k < 8; k++) {
            int s = k + (k >= n);
            float w = aw[n * 8 + k];
            bf16x8 psv = *(const bf16x8*)(sPB + s * O2 + O + cc * 8);
            const ushort* qp = (const ushort*)&psv;
#pragma unroll
            for (int j = 0; j < 8; j++)
                acc8[j] += w * gelu_fast(pdf[j] + b2f(qp[j]));
        }
        ushort o8[8];
#pragma unroll
        for (int j = 0; j < 8; j++) o8[j] = f2b(acc8[j]);
        *(bf16x8*)(Gout + (size_t)(g * 9 + n) * ldG + cc * 8) = *(const bf16x8*)o8;
    }
}

// ---------------------------------------------------------------------------
// Fused upd-epilogue + LayerNorm, wave-per-row (no block barriers),
// bf16 partials P0:
//   t = bf16(P0) + ub[c] + vb[c]*S[n] + posU[(n%9)*O+c];
//   h = gelu(t) + skip(bf16);  LN(h) -> outB bf16 (row remap) or outF fp32
// Block = 4 waves = 4 rows; O/64 elems per lane (4 or 8).
// ---------------------------------------------------------------------------
__global__ __launch_bounds__(256) void ln_kernel(
    const ushort* __restrict__ P0,
    const float* __restrict__ ub, const float* __restrict__ vb,
    const float* __restrict__ S, const float* __restrict__ posU,
    const ushort* __restrict__ PBs, int ld5,
    const float* __restrict__ gw, const float* __restrict__ bw,
    ushort* outB, int ldoB, int rowsplit, float* outF, int O)
{
    const int wid = threadIdx.x >> 6, lane = threadIdx.x & 63;
    const int n = blockIdx.x * 4 + wid;
    const float sv = S[n];
    const ushort* p0 = P0 + (size_t)n * O;
    const ushort* sr = PBs + (size_t)n * ld5;
    const float* pu = posU + (size_t)(n % 9) * O;
    const int q = O >> 6;              // 4 or 8 elems per lane
    const int c0 = lane * q;

    float vals[8];
    float sum = 0.f;
    if (O == 256) {
        ushort4 pv = *(const ushort4*)(p0 + c0);
        ushort4 sk = *(const ushort4*)(sr + c0);
        float4 uu = *(const float4*)(ub + c0);
        float4 vv = *(const float4*)(vb + c0);
        float4 gg = *(const float4*)(pu + c0);
        const ushort tp[4] = {pv.x, pv.y, pv.z, pv.w};
        const ushort ts[4] = {sk.x, sk.y, sk.z, sk.w};
        const float tu[4] = {uu.x, uu.y, uu.z, uu.w};
        const float tv[4] = {vv.x, vv.y, vv.z, vv.w};
        const float tg[4] = {gg.x, gg.y, gg.z, gg.w};
#pragma unroll
        for (int j = 0; j < 4; j++) {
            float t = b2f(tp[j]) + tu[j] + tv[j] * sv + tg[j];
            vals[j] = gelu_f(t) + b2f(ts[j]);
            sum += vals[j];
        }
    } else {                           // O == 512
        bf16x8 pv = *(const bf16x8*)(p0 + c0);
        bf16x8 sk = *(const bf16x8*)(sr + c0);
        const ushort* tp = (const ushort*)&pv;
        const ushort* ts = (const ushort*)&sk;
        float4 u0 = *(const float4*)(ub + c0), u1 = *(const float4*)(ub + c0 + 4);
        float4 v0 = *(const float4*)(vb + c0), v1 = *(const float4*)(vb + c0 + 4);
        float4 g0 = *(const float4*)(pu + c0), g1 = *(const float4*)(pu + c0 + 4);
        const float tu[8] = {u0.x,u0.y,u0.z,u0.w, u1.x,u1.y,u1.z,u1.w};
        const float tv[8] = {v0.x,v0.y,v0.z,v0.w, v1.x,v1.y,v1.z,v1.w};
        const float tg[8] = {g0.x,g0.y,g0.z,g0.w, g1.x,g1.y,g1.z,g1.w};
#pragma unroll
        for (int j = 0; j < 8; j++) {
            float t = b2f(tp[j]) + tu[j] + tv[j] * sv + tg[j];
            vals[j] = gelu_f(t) + b2f(ts[j]);
            sum += vals[j];
        }
    }

#pragma unroll
    for (int off = 32; off; off >>= 1) sum += __shfl_xor(sum, off, 64);
    const float mu = sum / (float)O;
    float var = 0.f;
#pragma unroll
    for (int j = 0; j < 8; j++) {
        if (j < q) { float d = vals[j] - mu; var += d * d; }
    }
#pragma unroll
    for (int off = 32; off; off >>= 1) var += __shfl_xor(var, off, 64);
    const float rstd = rsqrtf(var / (float)O + 1e-5f);

    int orow = n, coloff = 0;
    if (n >= rowsplit) { orow = n - rowsplit; coloff = 256; }

    if (outB) {
        ushort o[8];
#pragma unroll
        for (int j = 0; j < 8; j++) {
            if (j < q) o[j] = f2b((vals[j] - mu) * rstd * gw[c0 + j] + bw[c0 + j]);
        }
        ushort* dst = outB + (size_t)orow * ldoB + coloff + c0;
        if (q == 4) *(ushort4*)dst = *(const ushort4*)o;
        else        *(bf16x8*)dst = *(const bf16x8*)o;
    }
    if (outF) {
        float* dst = outF + (size_t)n * O + c0;
#pragma unroll
        for (int j = 0; j < 8; j++) {
            if (j < q) dst[j] = (vals[j] - mu) * rstd * gw[c0 + j] + bw[c0 + j];
        }
    }
}

// ---------------------------------------------------------------------------
// prep: concat biases, pos tables (posPB/posU), vb, pw2 bf16 copies,
//       and feat_low/feat_high fp32->bf16 conversion (merged f2b)
// ---------------------------------------------------------------------------
__global__ void prep_kernel(
    const float* __restrict__ pw1_b1, const float* __restrict__ att1_b1, const float* __restrict__ skip_b1,
    const float* __restrict__ pw1_b2, const float* __restrict__ att1_b2, const float* __restrict__ skip_b2,
    const float* __restrict__ pos_table,
    const float* __restrict__ s1_pw1, const float* __restrict__ s1_att, const float* __restrict__ s1_skp,
    const float* __restrict__ s2_pw1, const float* __restrict__ s2_att, const float* __restrict__ s2_skp,
    const float* __restrict__ pw2_b1, const float* __restrict__ upd_w1,
    const float* __restrict__ pw2_b2, const float* __restrict__ upd_w2,
    const float* __restrict__ pw2_w1, const float* __restrict__ pw2_w2,
    const float* __restrict__ feat_low, const float* __restrict__ feat_high,
    float* biasC1, float* biasC2,
    float* posPB1, float* posPB2, float* posU1, float* posU2,
    float* vb1, float* vb2, ushort* pw2f1, ushort* pw2f2, ushort* featB)
{
    int i = blockIdx.x * 256 + threadIdx.x;
    if (i < 1280) {
        float v;
        if (i < 256) v = pw1_b1[i];
        else if (i < 512) v = 0.f;
        else if (i < 768) v = att1_b1[i - 512];
        else if (i < 1024) v = 0.f;
        else v = skip_b1[i - 1024];
        biasC1[i] = v;
        return;
    }
    i -= 1280;
    if (i < 2560) {
        float v;
        if (i < 512) v = pw1_b2[i];
        else if (i < 1024) v = 0.f;
        else if (i < 1536) v = att1_b2[i - 1024];
        else if (i < 2048) v = 0.f;
        else v = skip_b2[i - 2048];
        biasC2[i] = v;
        return;
    }
    i -= 2560;
    if (i < 9 * 1280) {   // posPB1[r][n]
        int r = i / 1280, n = i - r * 1280;
        int sec = n >> 8, c = n & 255;
        const float* src; int row0;
        if (sec == 0) { src = s1_pw1; row0 = 256; }
        else if (sec == 1) { src = s1_pw1; row0 = 576; }
        else if (sec == 2) { src = s1_att; row0 = 512; }
        else if (sec == 3) { src = s1_att; row0 = 576; }
        else { src = s1_skp; row0 = 256; }
        float a = 0.f;
        for (int k = 0; k < 64; k++) a += pos_table[r * 64 + k] * src[(size_t)(row0 + k) * 256 + c];
        posPB1[i] = a;
        return;
    }
    i -= 9 * 1280;
    if (i < 9 * 2560) {   // posPB2[r][n]
        int r = i / 2560, n = i - r * 2560;
        int sec = n >> 9, c = n & 511;
        const float* src; int row0;
        if (sec == 0) { src = s2_pw1; row0 = 512; }
        else if (sec == 1) { src = s2_pw1; row0 = 1088; }
        else if (sec == 2) { src = s2_att; row0 = 1024; }
        else if (sec == 3) { src = s2_att; row0 = 1088; }
        else { src = s2_skp; row0 = 512; }
        float a = 0.f;
        for (int k = 0; k < 64; k++) a += pos_table[r * 64 + k] * src[(size_t)(row0 + k) * 512 + c];
        posPB2[i] = a;
        return;
    }
    i -= 9 * 2560;
    if (i < 9 * 256) {    // posU1
        int r = i >> 8, c = i & 255;
        float a = 0.f;
        for (int k = 0; k < 64; k++) a += pos_table[r * 64 + k] * upd_w1[(size_t)(256 + k) * 256 + c];
        posU1[i] = a;
        return;
    }
    i -= 9 * 256;
    if (i < 9 * 512) {    // posU2
        int r = i >> 9, c = i & 511;
        float a = 0.f;
        for (int k = 0; k < 64; k++) a += pos_table[r * 64 + k] * upd_w2[(size_t)(512 + k) * 512 + c];
        posU2[i] = a;
        return;
    }
    i -= 9 * 512;
    if (i < 256) {        // vb1[n] = sum_j pw2_b1[j] * upd_w1[(320+j)][n]
        float a = 0.f;
        for (int j = 0; j < 256; j++) a += pw2_b1[j] * upd_w1[(size_t)(320 + j) * 256 + i];
        vb1[i] = a;
        return;
    }
    i -= 256;
    if (i < 512) {        // vb2
        float a = 0.f;
        for (int j = 0; j < 512; j++) a += pw2_b2[j] * upd_w2[(size_t)(576 + j) * 512 + i];
        vb2[i] = a;
        return;
    }
    i -= 512;
    if (i < 256 * 256) { pw2f1[i] = f2b(pw2_w1[i]); return; }
    i -= 256 * 256;
    if (i < 512 * 512) { pw2f2[i] = f2b(pw2_w2[i]); return; }
    i -= 512 * 512;
    if (i < NN * 512 / 4) {   // feat_low -> featB bf16
        float4 v = ((const float4*)feat_low)[i];
        ushort4 o;
        o.x = f2b(v.x); o.y = f2b(v.y); o.z = f2b(v.z); o.w = f2b(v.w);
        ((ushort4*)featB)[i] = o;
        return;
    }
    i -= NN * 512 / 4;
    if (i < NN * 1024 / 4) {  // feat_high -> featB + NN*512
        float4 v = ((const float4*)feat_high)[i];
        ushort4 o;
        o.x = f2b(v.x); o.y = f2b(v.y); o.z = f2b(v.z); o.w = f2b(v.w);
        ((ushort4*)(featB + (size_t)NN * 512))[i] = o;
    }
}

// ---------------------------------------------------------------------------
// head: pool(9 rows) + cls1 (gelu) + cls2, 4 graphs per block
// ---------------------------------------------------------------------------
__global__ __launch_bounds__(256) void head_kernel(
    const float* __restrict__ h2,
    const float* __restrict__ cls1_w, const float* __restrict__ cls1_b,
    const float* __restrict__ cls2_w, const float* __restrict__ cls2_b,
    float* __restrict__ out)
{
    __shared__ float pooled[4][512];
    __shared__ float hid[4][256];
    const int b = blockIdx.x, tid = threadIdx.x;

    for (int idx = tid; idx < 4 * 512; idx += 256) {
        int gi = idx >> 9, c = idx & 511;
        const float* base = h2 + (size_t)((b * 4 + gi) * 9) * 512 + c;
        float s = 0.f;
#pragma unroll
        for (int k = 0; k < NPG; k++) s += base[(size_t)k * 512];
        pooled[gi][c] = s;
    }
    __syncthreads();

    {
        float acc[4] = {0.f, 0.f, 0.f, 0.f};
        for (int c = 0; c < 512; c++) {
            float w = cls1_w[(size_t)c * 256 + tid];
#pragma unroll
            for (int gi = 0; gi < 4; gi++) acc[gi] += pooled[gi][c] * w;
        }
        float bb = cls1_b[tid];
#pragma unroll
        for (int gi = 0; gi < 4; gi++) hid[gi][tid] = gelu_f(acc[gi] + bb);
    }
    __syncthreads();

    {
        int gi = tid >> 6, lane = tid & 63;
        float p = 0.f;
#pragma unroll
        for (int i = 0; i < 4; i++) p += hid[gi][lane + 64 * i] * cls2_w[lane + 64 * i];
#pragma unroll
        for (int off = 32; off; off >>= 1) p += __shfl_down(p, off, 64);
        if (lane == 0) out[b * 4 + gi] = p + cls2_b[0];
    }
}

// ---------------------------------------------------------------------------
// Host side
// ---------------------------------------------------------------------------
static inline void mg(hipStream_t st, int M, int N, int K,
                      const ushort* A, int lda, const ushort* Wt, int ldw,
                      const float* bias1, const float* prow, int ldp,
                      ushort* outB, int ldo)
{
    dim3 grid(N / 128, M / 128);
    mgemm<<<grid, dim3(256), 0, st>>>(A, lda, Wt, ldw, bias1, prow, ldp,
                                      outB, ldo, K);
}

extern "C" void kernel_launch(void* const* d_in, const int* in_sizes, int n_in,
                              void* d_out, int out_size, void* d_ws, size_t ws_size,
                              hipStream_t stream)
{
    (void)in_sizes; (void)n_in; (void)out_size; (void)ws_size;
    const float* feat_low   = (const float*)d_in[0];
    const float* feat_high  = (const float*)d_in[1];
    const float* pos_table  = (const float*)d_in[4];
    const float* proj_low_w  = (const float*)d_in[5];
    const float* proj_low_b  = (const float*)d_in[6];
    const float* proj_high_w = (const float*)d_in[7];
    const float* proj_high_b = (const float*)d_in[8];
    const float* cls1_w = (const float*)d_in[37];
    const float* cls1_b = (const float*)d_in[38];
    const float* cls2_w = (const float*)d_in[39];
    const float* cls2_b = (const float*)d_in[40];
    float* out = (float*)d_out;

    const float* s1_pw1 = (const float*)d_in[9];
    const float* s1_att = (const float*)d_in[13];
    const float* s1_upd = (const float*)d_in[17];
    const float* s1_skp = (const float*)d_in[21];
    const float* s2_pw1 = (const float*)d_in[23];
    const float* s2_att = (const float*)d_in[27];
    const float* s2_upd = (const float*)d_in[31];
    const float* s2_skp = (const float*)d_in[35];

    const float* att2_w1 = (const float*)d_in[15];
    const float* upd_b1  = (const float*)d_in[18];
    const float* ln_g1   = (const float*)d_in[19];
    const float* ln_b1   = (const float*)d_in[20];
    const float* att2_w2 = (const float*)d_in[29];
    const float* upd_b2  = (const float*)d_in[32];
    const float* ln_g2   = (const float*)d_in[33];
    const float* ln_b2   = (const float*)d_in[34];

    // ---- workspace layout (256B aligned) ----
    char* base = (char*)d_ws;
    size_t cur = 0;
    auto alloc = [&](size_t bytes) { void* p = base + cur; cur += (bytes + 255) & ~(size_t)255; return p; };
    void*   PBreg = alloc((size_t)NN * 2560 * 2);   // PB (s1: 18432x1280, s2: 9216x2560); featB alias
    ushort* PB    = (ushort*)PBreg;
    ushort* featB = (ushort*)PBreg;
    void*   IX1reg = alloc((size_t)NN2 * 512 * 2);  // ixa1 bf16; h2 fp32 alias (disjoint in time)
    ushort* ixa1  = (ushort*)IX1reg;
    float*  h2    = (float*)IX1reg;
    ushort* ixa2  = (ushort*)alloc((size_t)NN * 1024 * 2);
    ushort* PT    = (ushort*)alloc((size_t)NN2 * 512 * 2);  // upd bf16 partials
    float*  S     = (float*)alloc((size_t)NN2 * 4);
    float*  biasC1 = (float*)alloc(1280 * 4);
    float*  biasC2 = (float*)alloc(2560 * 4);
    float*  posPB1 = (float*)alloc(9 * 1280 * 4);
    float*  posPB2 = (float*)alloc(9 * 2560 * 4);
    float*  posU1  = (float*)alloc(9 * 256 * 4);
    float*  posU2  = (float*)alloc(9 * 512 * 4);
    float*  vb1   = (float*)alloc(256 * 4);
    float*  vb2   = (float*)alloc(512 * 4);
    ushort* wbuf  = (ushort*)alloc((size_t)3400000 * 2);

    // ---- weight transpose jobs (x-parts only; pos handled via prow tables) ----
    TJobsArg ja;
    long woff[16];
    {
        struct J { const float* s; int K, N, off0, ldo; long sz; };
        J js[NJOBS] = {
            {proj_low_w,  512, 256, 0, 512, 512L * 256},     // 0 projL
            {proj_high_w, 1024, 256, 0, 1024, 1024L * 256},  // 1 projH
            {s1_pw1, 256, 256, 0, 256, 256L * 256},          // 2 big5-1: pw1d
            {s1_pw1, 256, 256, 320, 256, 256L * 256},        // 3 pw1s
            {s1_att, 256, 256, 0, 256, 256L * 256},          // 4 attd
            {s1_att, 256, 256, 256, 256, 256L * 256},        // 5 atts
            {s1_skp, 256, 256, 0, 256, 256L * 256},          // 6 skip
            {s1_upd, 256, 256, 0, 512, 512L * 256},          // 7 updW1 (x cols)
            {s1_upd, 256, 256, 320, 256, 256L * 256},        // 8 updbT1 (aggr rows)
            {s2_pw1, 512, 512, 0, 512, 512L * 512},          // 9 big5-2: pw1d
            {s2_pw1, 512, 512, 576, 512, 512L * 512},        // 10 pw1s
            {s2_att, 512, 512, 0, 512, 512L * 512},          // 11 attd
            {s2_att, 512, 512, 512, 512, 512L * 512},        // 12 atts
            {s2_skp, 512, 512, 0, 512, 512L * 512},          // 13 skip
            {s2_upd, 512, 512, 0, 1024, 1024L * 512},        // 14 updW2 (x cols)
            {s2_upd, 512, 512, 576, 512, 512L * 512},        // 15 updbT2
        };
        long off = 0;
        for (int i = 0; i < NJOBS; i++) {
            ja.src[i] = js[i].s; ja.K[i] = js[i].K; ja.N[i] = js[i].N;
            ja.off0[i] = js[i].off0; ja.ldo[i] = js[i].ldo;
            ja.dst[i] = off; woff[i] = off;
            off += js[i].sz;
        }
    }
    long pw2off1 = woff[15] + 512L * 512;
    long pw2off2 = pw2off1 + 256L * 256;
    tw_kernel<<<dim3(256, NJOBS), dim3(256), 0, stream>>>(ja, wbuf);

    ushort* wBig5_1 = wbuf + woff[2];
    ushort* updW1   = wbuf + woff[7];
    ushort* updbT1  = wbuf + woff[8];
    ushort* wBig5_2 = wbuf + woff[9];
    ushort* updW2   = wbuf + woff[14];
    ushort* updbT2  = wbuf + woff[15];
    ushort* pw2f1   = wbuf + pw2off1;
    ushort* pw2f2   = wbuf + pw2off2;

    // ---- prep (biases, pos tables, vb, pw2 bf16, feat->bf16) ----
    {
        long tot = 1280 + 2560 + 9 * 1280 + 9 * 2560 + 9 * 256 + 9 * 512
                 + 256 + 512 + 256 * 256 + 512 * 512
                 + (long)NN * 512 / 4 + (long)NN * 1024 / 4;
        prep_kernel<<<dim3((unsigned)((tot + 255) / 256)), dim3(256), 0, stream>>>(
            (const float*)d_in[10], (const float*)d_in[14], (const float*)d_in[22],
            (const float*)d_in[24], (const float*)d_in[28], (const float*)d_in[36],
            pos_table,
            s1_pw1, s1_att, s1_skp, s2_pw1, s2_att, s2_skp,
            (const float*)d_in[12], s1_upd, (const float*)d_in[26], s2_upd,
            (const float*)d_in[11], (const float*)d_in[25],
            feat_low, feat_high,
            biasC1, biasC2, posPB1, posPB2, posU1, posU2, vb1, vb2, pw2f1, pw2f2, featB);
    }

    // ---- Wcomb = pw2 @ updb, transposed into updW G-columns ----
    mg(stream, 256, 256, 256, updbT1, 256, pw2f1, 256, 0, 0, 0, updW1 + 256, 512);
    mg(stream, 512, 512, 512, updbT2, 512, pw2f2, 512, 0, 0, 0, updW2 + 512, 1024);

    // ---- projections: ONE fused dispatch, full-K, direct bf16 + bias ----
    {
        PJArg pa;
        pa.A[0] = featB;                      pa.lda[0] = 512;  pa.K[0] = 512;
        pa.A[1] = featB + (size_t)NN * 512;   pa.lda[1] = 1024; pa.K[1] = 1024;
        pa.W[0] = wbuf + woff[0];
        pa.W[1] = wbuf + woff[1];
        pa.bias[0] = proj_low_b;
        pa.bias[1] = proj_high_b;
        pa.out[0] = ixa1;
        pa.out[1] = ixa1 + (size_t)NN * 512;
        pjgemm<<<dim3(2, NN / 128, 2), dim3(256), 0, stream>>>(pa);
    }

    // ---- stage 1 (batched, M = 18432) ----
    mg(stream, NN2, 1280, 256, ixa1, 512, wBig5_1, 256, biasC1, posPB1, 1280, PB, 1280);
    edge_kernel_t<256><<<dim3(2 * NUM_GRAPHS), dim3(256), 0, stream>>>(
        PB, att2_w1, ixa1 + 256, 512, S);
    mg(stream, NN2, 256, 512, ixa1, 512, updW1, 512, 0, 0, 0, PT, 256);
    ln_kernel<<<dim3(NN2 / 4), dim3(256), 0, stream>>>(
        PT, upd_b1, vb1, S, posU1,
        PB + 4 * 256, 1280, ln_g1, ln_b1, ixa2, 1024, NN, 0, 256);

    // ---- stage 2 ----
    mg(stream, NN, 2560, 512, ixa2, 1024, wBig5_2, 512, biasC2, posPB2, 2560, PB, 2560);
    edge_kernel_t<512><<<dim3(NUM_GRAPHS), dim3(256), 0, stream>>>(
        PB, att2_w2, ixa2 + 512, 1024, S);
    mg(stream, NN, 512, 1024, ixa2, 1024, updW2, 1024, 0, 0, 0, PT, 512);
    ln_kernel<<<dim3(NN / 4), dim3(256), 0, stream>>>(
        PT, upd_b2, vb2, S, posU2,
        PB + 4 * 512, 2560, ln_g2, ln_b2, 0, 0, 1 << 30, h2, 512);

    // ---- head ----
    head_kernel<<<dim3(NUM_GRAPHS / 4), dim3(256), 0, stream>>>(h2, cls1_w, cls1_b, cls2_w, cls2_b, out);
}